// Round 3
// baseline (5315.575 us; speedup 1.0000x reference)
//
#include <hip/hip_runtime.h>
#include <hip/hip_bf16.h>

// ---------------------------------------------------------------------------
// PDNConv GNN, MI355X round 3: runtime dtype probe (bf16 vs f32 inputs).
// The reference file says float32 but the test labels say bf16 — instead of
// guessing, a probe kernel classifies x's bit patterns and every input read
// (and the output write) branches on the flag. Also: edge gates computed
// directly in CSR order (drops w_all, ws now ~69 MB), deg reads contiguous.
// ---------------------------------------------------------------------------

#define NN 50000
#define EE 600000
#define GG 256
#define HID 128
#define EDIM 16
#define EHID 64
#define NL 4
#define MIN_F 200
#define MH 256
#define MOUT 128
#define PH 512
#define PIN 256

typedef __hip_bfloat16 bf16;

__device__ __forceinline__ float bfl(unsigned u) { return __uint_as_float(u << 16); }
__device__ __forceinline__ float bfh(unsigned u) { return __uint_as_float(u & 0xffff0000u); }
__device__ __forceinline__ float b2f(bf16 x) { return __bfloat162float(x); }
// dtype-flag-aware element load: bf ? bf16[i] : f32[i]
__device__ __forceinline__ float ldf(const void* p, long i, bool bf) {
  return bf ? __bfloat162float(((const bf16*)p)[i]) : ((const float*)p)[i];
}
__device__ __forceinline__ unsigned short f2bf_bits(float v) {
  bf16 h = __float2bfloat16(v);
  return *reinterpret_cast<unsigned short*>(&h);
}

// ---------------- dtype probe ------------------------------------------------
// bf16 N(0,1) data: first 128 u16s all have exponent ~127 (sane).
// f32 data read as u16: half are mantissa fragments with random exponents
// -> expected ~80/128 sane. Threshold 112 separates by >8 sigma.
__global__ void probe_kernel(const unsigned short* __restrict__ xs, int* flag) {
  if (threadIdx.x == 0 && blockIdx.x == 0) {
    int sane = 0;
    for (int i = 0; i < 128; i++) {
      unsigned e = (xs[i] >> 7) & 0xFF;
      if (e >= 96 && e <= 159) sane++;
    }
    *flag = (sane >= 112) ? 1 : 0;  // 1 = bf16 inputs
  }
}

// ---------------- input -> f32 conversion (4 elems/thread) ------------------
__global__ __launch_bounds__(256) void cvt_any(const void* __restrict__ in,
                                               float* __restrict__ outp, int n4,
                                               const int* __restrict__ flag) {
  bool bf = *flag != 0;
  int i = blockIdx.x * 256 + threadIdx.x;
  if (i >= n4) return;
  float4 v;
  if (bf) {
    uint2 u = reinterpret_cast<const uint2*>(in)[i];
    v.x = bfl(u.x); v.y = bfh(u.x); v.z = bfl(u.y); v.w = bfh(u.y);
  } else {
    v = reinterpret_cast<const float4*>(in)[i];
  }
  reinterpret_cast<float4*>(outp)[i] = v;
}

// ---------------- CSR build: histogram / scan / fill ------------------------
__global__ __launch_bounds__(256) void count_kernel(const int* __restrict__ ei,
                                                    int* __restrict__ cnt) {
  int e = blockIdx.x * 256 + threadIdx.x;
  if (e >= EE) return;
  int c = ei[EE + e];
  c = min(max(c, 0), NN - 1);
  atomicAdd(&cnt[c], 1);
}

__global__ __launch_bounds__(256) void scan_kernel(const int* __restrict__ cnt,
                                                   int* __restrict__ offs) {
  __shared__ int ssum[256];
  int tid = threadIdx.x;
  const int STRIP = (NN + 255) / 256;  // 196
  int s0 = tid * STRIP;
  int s1 = min(s0 + STRIP, NN);
  int sum = 0;
  for (int i = s0; i < s1; i++) sum += cnt[i];
  ssum[tid] = sum;
  __syncthreads();
  if (tid == 0) {
    int acc = 0;
    for (int i = 0; i < 256; i++) { int v = ssum[i]; ssum[i] = acc; acc += v; }
    offs[NN] = acc;
  }
  __syncthreads();
  int run = ssum[tid];
  for (int i = s0; i < s1; i++) { offs[i] = run; run += cnt[i]; }
}

__global__ __launch_bounds__(256) void fill_kernel(const int* __restrict__ ei,
                                                   const int* __restrict__ offs,
                                                   int* __restrict__ cursor,
                                                   int* __restrict__ csr_src,
                                                   int* __restrict__ csr_eid) {
  int e = blockIdx.x * 256 + threadIdx.x;
  if (e >= EE) return;
  int c = ei[EE + e];
  c = min(max(c, 0), NN - 1);
  int pos = offs[c] + atomicAdd(&cursor[c], 1);
  pos = min(max(pos, 0), EE - 1);
  csr_src[pos] = ei[e];
  csr_eid[pos] = e;
}

// ---------------- edge-gate MLP, all 4 layers, writes in CSR order ----------
// csr_val[l*EE + k] = sigmoid(relu(attr[eid_k] @ mW1_l + mb1_l) @ mW2_l + mb2_l)
__global__ __launch_bounds__(256) void edge_mlp_kernel(
    const void* __restrict__ eattr, const void* __restrict__ mW1,
    const void* __restrict__ mb1, const void* __restrict__ mW2,
    const void* __restrict__ mb2, const int* __restrict__ csr_eid,
    float* __restrict__ csr_val, const int* __restrict__ flag) {
  bool bf = *flag != 0;
  __shared__ alignas(16) float sW1[NL][EHID][EDIM];  // transposed: k contiguous
  __shared__ float sb1[NL][EHID];
  __shared__ float sW2[NL][EHID];
  __shared__ float sb2[NL];
  int tid = threadIdx.x;
  for (int i = tid; i < NL * EDIM * EHID; i += 256) {
    int l = i / (EDIM * EHID);
    int rem = i - l * (EDIM * EHID);
    int k = rem / EHID;
    int j = rem - k * EHID;
    sW1[l][j][k] = ldf(mW1, i, bf);
  }
  for (int i = tid; i < NL * EHID; i += 256) {
    sb1[i / EHID][i % EHID] = ldf(mb1, i, bf);
    sW2[i / EHID][i % EHID] = ldf(mW2, i, bf);
  }
  if (tid < NL) sb2[tid] = ldf(mb2, tid, bf);
  __syncthreads();

  int k0 = (blockIdx.x * 256 + tid) * 4;
  float attr[4][EDIM];
#pragma unroll
  for (int t = 0; t < 4; t++) {
    int k = k0 + t;
    if (k < EE) {
      long eid = csr_eid[k];
      if (bf) {
        const uint4* p = reinterpret_cast<const uint4*>((const bf16*)eattr + eid * EDIM);
        uint4 u0 = p[0], u1 = p[1];
        attr[t][0] = bfl(u0.x);  attr[t][1] = bfh(u0.x);
        attr[t][2] = bfl(u0.y);  attr[t][3] = bfh(u0.y);
        attr[t][4] = bfl(u0.z);  attr[t][5] = bfh(u0.z);
        attr[t][6] = bfl(u0.w);  attr[t][7] = bfh(u0.w);
        attr[t][8] = bfl(u1.x);  attr[t][9] = bfh(u1.x);
        attr[t][10] = bfl(u1.y); attr[t][11] = bfh(u1.y);
        attr[t][12] = bfl(u1.z); attr[t][13] = bfh(u1.z);
        attr[t][14] = bfl(u1.w); attr[t][15] = bfh(u1.w);
      } else {
        const float4* p = reinterpret_cast<const float4*>((const float*)eattr + eid * EDIM);
#pragma unroll
        for (int q = 0; q < 4; q++) {
          float4 v = p[q];
          attr[t][q * 4 + 0] = v.x; attr[t][q * 4 + 1] = v.y;
          attr[t][q * 4 + 2] = v.z; attr[t][q * 4 + 3] = v.w;
        }
      }
    } else {
#pragma unroll
      for (int k2 = 0; k2 < EDIM; k2++) attr[t][k2] = 0.f;
    }
  }

  for (int l = 0; l < NL; l++) {
    float acc[4];
#pragma unroll
    for (int t = 0; t < 4; t++) acc[t] = sb2[l];
    for (int j = 0; j < EHID; j++) {
      const float4* wp = reinterpret_cast<const float4*>(&sW1[l][j][0]);
      float4 a0 = wp[0], a1 = wp[1], a2 = wp[2], a3 = wp[3];
      float wk[EDIM] = {a0.x, a0.y, a0.z, a0.w, a1.x, a1.y, a1.z, a1.w,
                        a2.x, a2.y, a2.z, a2.w, a3.x, a3.y, a3.z, a3.w};
      float bj = sb1[l][j], w2 = sW2[l][j];
#pragma unroll
      for (int t = 0; t < 4; t++) {
        float s = bj;
#pragma unroll
        for (int k2 = 0; k2 < EDIM; k2++) s = fmaf(attr[t][k2], wk[k2], s);
        acc[t] += fmaxf(s, 0.f) * w2;
      }
    }
    float4 r;
    r.x = 1.f / (1.f + __expf(-acc[0]));
    r.y = 1.f / (1.f + __expf(-acc[1]));
    r.z = 1.f / (1.f + __expf(-acc[2]));
    r.w = 1.f / (1.f + __expf(-acc[3]));
    if (k0 + 4 <= EE) {
      *reinterpret_cast<float4*>(&csr_val[(size_t)l * EE + k0]) = r;
    } else {
      float rr[4] = {r.x, r.y, r.z, r.w};
      for (int t = 0; t < 4; t++)
        if (k0 + t < EE) csr_val[(size_t)l * EE + k0 + t] = rr[t];
    }
  }
}

// ---------------- degree / dinv per layer (contiguous csr_val reads) --------
__global__ __launch_bounds__(256) void deg_kernel(const int* __restrict__ offs,
                                                  const float* __restrict__ csr_val,
                                                  float* __restrict__ dinv_all) {
  int n = blockIdx.x * 256 + threadIdx.x;
  if (n >= NN) return;
  int s = offs[n], e = offs[n + 1];
  float d0 = 1.f, d1 = 1.f, d2 = 1.f, d3 = 1.f;  // self-loop weight 1.0
  for (int k = s; k < e; k++) {
    d0 += csr_val[k];
    d1 += csr_val[EE + k];
    d2 += csr_val[2 * (size_t)EE + k];
    d3 += csr_val[3 * (size_t)EE + k];
  }
  dinv_all[n] = rsqrtf(d0);
  dinv_all[NN + n] = rsqrtf(d1);
  dinv_all[2 * NN + n] = rsqrtf(d2);
  dinv_all[3 * NN + n] = rsqrtf(d3);
}

// csr_val[l][k] *= dinv_l[src_k]   (dinv[dst] factor applied in aggregate)
__global__ __launch_bounds__(256) void csr_scale_kernel(const int* __restrict__ csr_src,
                                                        const float* __restrict__ dinv_all,
                                                        float* __restrict__ csr_val) {
  int k = blockIdx.x * 256 + threadIdx.x;
  if (k >= EE) return;
  int s = csr_src[k];
  s = min(max(s, 0), NN - 1);
#pragma unroll
  for (int l = 0; l < NL; l++)
    csr_val[(size_t)l * EE + k] *= dinv_all[(size_t)l * NN + s];
}

// ---------------- node GEMM: out[N,128] = A[N,128] @ W[128,128] (+b)(+relu) -
__global__ __launch_bounds__(256) void gemm_nodes(const float* __restrict__ A,
                                                  const void* __restrict__ W, long Woff,
                                                  const void* __restrict__ bias, long boff,
                                                  float* __restrict__ outp, int relu,
                                                  const int* __restrict__ flag) {
  bool bf = *flag != 0;
  __shared__ alignas(16) float sA[32 * 132];
  __shared__ alignas(16) unsigned short sW[HID * HID];
  int tid = threadIdx.x;
  int rbase = blockIdx.x * 32;

  if (bf) {
    const uint4* Wv = reinterpret_cast<const uint4*>((const bf16*)W + Woff);
    uint4* sWv = reinterpret_cast<uint4*>(sW);
#pragma unroll
    for (int i = 0; i < 8; i++) sWv[tid + 256 * i] = Wv[tid + 256 * i];
  } else {
    const float* Wf = (const float*)W + Woff;
    for (int i = tid; i < HID * HID; i += 256) sW[i] = f2bf_bits(Wf[i]);
  }

#pragma unroll
  for (int i = 0; i < 4; i++) {
    int idx = tid + 256 * i;
    int r = idx >> 5, k4 = idx & 31;
    int row = rbase + r;
    float4 v = make_float4(0.f, 0.f, 0.f, 0.f);
    if (row < NN) v = reinterpret_cast<const float4*>(A)[(size_t)row * 32 + k4];
    *reinterpret_cast<float4*>(&sA[r * 132 + k4 * 4]) = v;
  }
  __syncthreads();

  int tx = tid & 31, ty = tid >> 5;
  int col0 = tx * 4, row0 = ty * 4;
  float acc[4][4];
#pragma unroll
  for (int r = 0; r < 4; r++)
#pragma unroll
    for (int c = 0; c < 4; c++) acc[r][c] = 0.f;

#pragma unroll
  for (int kb = 0; kb < HID; kb += 4) {
    float a[4][4];
#pragma unroll
    for (int r = 0; r < 4; r++) {
      float4 v = *reinterpret_cast<const float4*>(&sA[(row0 + r) * 132 + kb]);
      a[r][0] = v.x; a[r][1] = v.y; a[r][2] = v.z; a[r][3] = v.w;
    }
#pragma unroll
    for (int kk = 0; kk < 4; kk++) {
      uint2 wv = *reinterpret_cast<const uint2*>(&sW[(kb + kk) * HID + col0]);
      float w0 = bfl(wv.x), w1 = bfh(wv.x), w2 = bfl(wv.y), w3 = bfh(wv.y);
#pragma unroll
      for (int r = 0; r < 4; r++) {
        acc[r][0] = fmaf(a[r][kk], w0, acc[r][0]);
        acc[r][1] = fmaf(a[r][kk], w1, acc[r][1]);
        acc[r][2] = fmaf(a[r][kk], w2, acc[r][2]);
        acc[r][3] = fmaf(a[r][kk], w3, acc[r][3]);
      }
    }
  }

  float b0 = 0.f, b1 = 0.f, b2 = 0.f, b3 = 0.f;
  if (boff >= 0) {
    b0 = ldf(bias, boff + col0, bf);     b1 = ldf(bias, boff + col0 + 1, bf);
    b2 = ldf(bias, boff + col0 + 2, bf); b3 = ldf(bias, boff + col0 + 3, bf);
  }
#pragma unroll
  for (int r = 0; r < 4; r++) {
    int row = rbase + row0 + r;
    if (row < NN) {
      float4 o;
      o.x = acc[r][0] + b0; o.y = acc[r][1] + b1;
      o.z = acc[r][2] + b2; o.w = acc[r][3] + b3;
      if (relu) {
        o.x = fmaxf(o.x, 0.f); o.y = fmaxf(o.y, 0.f);
        o.z = fmaxf(o.z, 0.f); o.w = fmaxf(o.w, 0.f);
      }
      *reinterpret_cast<float4*>(&outp[(size_t)row * HID + col0]) = o;
    }
  }
}

// ---------------- aggregation ------------------------------------------------
// out[n] = dinv[n]*(sum_k val_k*hl[src_k]) + dinv[n]^2*hl[n] + bias
__global__ __launch_bounds__(128) void aggregate_kernel(const float* __restrict__ hl,
                                                        const int* __restrict__ offs,
                                                        const int* __restrict__ csr_src,
                                                        const float* __restrict__ csr_val,
                                                        const float* __restrict__ dinv,
                                                        const void* __restrict__ bias, long boff,
                                                        float* __restrict__ outp,
                                                        const int* __restrict__ flag) {
  bool bf = *flag != 0;
  int n = blockIdx.x;
  int c = threadIdx.x;
  __shared__ int s_src[128];
  __shared__ float s_val[128];
  int start = offs[n], end = offs[n + 1];
  float acc = 0.f;
  for (int base = start; base < end; base += 128) {
    int k = base + c;
    if (k < end) {
      int sr = csr_src[k];
      s_src[c] = min(max(sr, 0), NN - 1);
      s_val[c] = csr_val[k];
    }
    __syncthreads();
    int m = min(128, end - base);
    for (int j = 0; j < m; j++)
      acc = fmaf(s_val[j], hl[(size_t)s_src[j] * HID + c], acc);
    __syncthreads();
  }
  float dn = dinv[n];
  outp[(size_t)n * HID + c] =
      dn * acc + dn * dn * hl[(size_t)n * HID + c] + ldf(bias, boff + c, bf);
}

// ---------------- mean pool per graph (sorted batch_index) ------------------
__global__ __launch_bounds__(128) void pool_kernel(const float* __restrict__ h,
                                                   const int* __restrict__ batch,
                                                   float* __restrict__ cat) {
  int g = blockIdx.x, c = threadIdx.x;
  int lo = 0, hi = NN;
  while (lo < hi) { int mid = (lo + hi) >> 1; if (batch[mid] < g) lo = mid + 1; else hi = mid; }
  int start = lo;
  hi = NN;
  while (lo < hi) { int mid = (lo + hi) >> 1; if (batch[mid] < g + 1) lo = mid + 1; else hi = mid; }
  int end = lo;
  float s = 0.f;
  for (int n = start; n < end; n++) s += h[(size_t)n * HID + c];
  float cntf = (float)(end - start);
  cat[(size_t)g * PIN + c] = s / fmaxf(cntf, 1.f);
}

// ---------------- small dense GEMM (G rows) ---------------------------------
__global__ __launch_bounds__(256) void gemm_small(const float* __restrict__ A,
                                                  const void* __restrict__ W,
                                                  const void* __restrict__ bias,
                                                  float* __restrict__ outp, int M, int K,
                                                  int Nout, int out_ld, int relu,
                                                  const int* __restrict__ flag) {
  bool bf = *flag != 0;
  int idx = blockIdx.x * 256 + threadIdx.x;
  if (idx >= M * Nout) return;
  int row = idx / Nout, col = idx - row * Nout;
  const float* a = A + (size_t)row * K;
  float acc = ldf(bias, col, bf);
  for (int k = 0; k < K; k++) acc = fmaf(a[k], ldf(W, (long)k * Nout + col, bf), acc);
  if (relu) acc = fmaxf(acc, 0.f);
  outp[(size_t)row * out_ld + col] = acc;
}

// ---------------- final [G,512] @ [512,1] + b -> out (dtype per flag) -------
__global__ __launch_bounds__(64) void final_kernel(const float* __restrict__ A,
                                                   const void* __restrict__ W,
                                                   const void* __restrict__ b,
                                                   void* __restrict__ outp,
                                                   const int* __restrict__ flag) {
  bool bf = *flag != 0;
  int g = blockIdx.x, lane = threadIdx.x;
  float s = 0.f;
  for (int k = lane; k < PH; k += 64) s = fmaf(A[(size_t)g * PH + k], ldf(W, k, bf), s);
#pragma unroll
  for (int off = 32; off > 0; off >>= 1) s += __shfl_down(s, off);
  if (lane == 0) {
    float r = s + ldf(b, 0, bf);
    if (bf) ((bf16*)outp)[g] = __float2bfloat16(r);
    else    ((float*)outp)[g] = r;
  }
}

// ---------------------------------------------------------------------------
extern "C" void kernel_launch(void* const* d_in, const int* in_sizes, int n_in,
                              void* d_out, int out_size, void* d_ws, size_t ws_size,
                              hipStream_t stream) {
  const void* x      = d_in[0];
  const int*  ei     = (const int*)d_in[1];
  const void* eattr  = d_in[2];
  const int*  batch  = (const int*)d_in[3];
  const void* molf   = d_in[4];
  const void* lin_W  = d_in[5];
  const void* mW1    = d_in[6];
  const void* mb1    = d_in[7];
  const void* mW2    = d_in[8];
  const void* mb2    = d_in[9];
  const void* cbias  = d_in[10];
  const void* gW     = d_in[11];
  const void* gb     = d_in[12];
  const void* mlpW0  = d_in[13];
  const void* mlpb0  = d_in[14];
  const void* mlpW1  = d_in[15];
  const void* mlpb1  = d_in[16];
  const void* mlpW2  = d_in[17];
  const void* mlpb2  = d_in[18];
  const void* mlpW3  = d_in[19];
  const void* mlpb3  = d_in[20];
  const void* predW0 = d_in[21];
  const void* predb0 = d_in[22];
  const void* predW1 = d_in[23];
  const void* predb1 = d_in[24];
  const void* outW   = d_in[25];
  const void* outb   = d_in[26];

  char* base = (char*)d_ws;
  size_t off = 0;
  auto alloc = [&](size_t bytes) -> char* {
    char* p = base + off;
    off = (off + bytes + 255) & ~(size_t)255;
    return p;
  };
  float* bufA     = (float*)alloc((size_t)NN * HID * 4);
  float* bufB     = (float*)alloc((size_t)NN * HID * 4);
  float* dinv_all = (float*)alloc((size_t)NL * NN * 4);
  int*   cnt      = (int*)alloc((size_t)NN * 4);
  int*   offs     = (int*)alloc((size_t)(NN + 1) * 4);
  int*   cursor   = (int*)alloc((size_t)NN * 4);
  int*   csr_src  = (int*)alloc((size_t)EE * 4);
  int*   csr_eid  = (int*)alloc((size_t)EE * 4);
  float* csr_val  = (float*)alloc((size_t)NL * EE * 4);
  int*   flag     = (int*)alloc(256);
  float* molf32   = (float*)alloc((size_t)GG * MIN_F * 4);
  float* m0       = (float*)alloc((size_t)GG * MH * 4);
  float* m1       = (float*)alloc((size_t)GG * MH * 4);
  float* cat      = (float*)alloc((size_t)GG * PIN * 4);
  float* p0       = (float*)alloc((size_t)GG * PH * 4);
  float* p1       = (float*)alloc((size_t)GG * PH * 4);

  hipMemsetAsync(cnt, 0, (size_t)NN * 4, stream);
  hipMemsetAsync(cursor, 0, (size_t)NN * 4, stream);

  // dtype probe first — everything downstream branches on it
  probe_kernel<<<1, 64, 0, stream>>>((const unsigned short*)x, flag);

  // x -> f32
  {
    int n4 = NN * HID / 4;
    cvt_any<<<(n4 + 255) / 256, 256, 0, stream>>>(x, bufA, n4, flag);
  }
  // CSR build
  count_kernel<<<(EE + 255) / 256, 256, 0, stream>>>(ei, cnt);
  scan_kernel<<<1, 256, 0, stream>>>(cnt, offs);
  fill_kernel<<<(EE + 255) / 256, 256, 0, stream>>>(ei, offs, cursor, csr_src, csr_eid);
  // edge gates (CSR order), degrees, scaling
  edge_mlp_kernel<<<(EE + 1023) / 1024, 256, 0, stream>>>(eattr, mW1, mb1, mW2, mb2,
                                                          csr_eid, csr_val, flag);
  deg_kernel<<<(NN + 255) / 256, 256, 0, stream>>>(offs, csr_val, dinv_all);
  csr_scale_kernel<<<(EE + 255) / 256, 256, 0, stream>>>(csr_src, dinv_all, csr_val);

  // GCN layers
  float* h = bufA;
  float* t = bufB;
  const int gemm_blocks = (NN + 31) / 32;
  for (int l = 0; l < NL; l++) {
    gemm_nodes<<<gemm_blocks, 256, 0, stream>>>(h, lin_W, (long)l * HID * HID,
                                                nullptr, -1, t, 0, flag);
    aggregate_kernel<<<NN, 128, 0, stream>>>(t, offs, csr_src, csr_val + (size_t)l * EE,
                                             dinv_all + (size_t)l * NN, cbias,
                                             (long)l * HID, h, flag);
    gemm_nodes<<<gemm_blocks, 256, 0, stream>>>(h, gW, (long)l * HID * HID,
                                                gb, (long)l * HID, t, 1, flag);
    float* tmp = h; h = t; t = tmp;
  }

  // pooling -> cat[:, 0:128]
  pool_kernel<<<GG, 128, 0, stream>>>(h, batch, cat);

  // molecular MLP -> cat[:, 128:256]
  {
    int n4 = GG * MIN_F / 4;
    cvt_any<<<(n4 + 255) / 256, 256, 0, stream>>>(molf, molf32, n4, flag);
  }
  gemm_small<<<(GG * MH + 255) / 256, 256, 0, stream>>>(molf32, mlpW0, mlpb0, m0, GG, MIN_F, MH, MH, 1, flag);
  gemm_small<<<(GG * MH + 255) / 256, 256, 0, stream>>>(m0, mlpW1, mlpb1, m1, GG, MH, MH, MH, 1, flag);
  gemm_small<<<(GG * MH + 255) / 256, 256, 0, stream>>>(m1, mlpW2, mlpb2, m0, GG, MH, MH, MH, 1, flag);
  gemm_small<<<(GG * MOUT + 255) / 256, 256, 0, stream>>>(m0, mlpW3, mlpb3, cat + MOUT, GG, MH, MOUT, PIN, 1, flag);

  // predictor
  gemm_small<<<(GG * PH + 255) / 256, 256, 0, stream>>>(cat, predW0, predb0, p0, GG, PIN, PH, PH, 1, flag);
  gemm_small<<<(GG * PH + 255) / 256, 256, 0, stream>>>(p0, predW1, predb1, p1, GG, PH, PH, PH, 1, flag);
  final_kernel<<<GG, 64, 0, stream>>>(p1, outW, outb, d_out, flag);
}

// Round 4
// 1532.178 us; speedup vs baseline: 3.4693x; 3.4693x over previous
//
#include <hip/hip_runtime.h>
#include <hip/hip_bf16.h>

// ---------------------------------------------------------------------------
// PDNConv GNN, MI355X round 4.
// Round-3 profile: old gemm_nodes had VGPR=256 -> scratch spill -> 1.4 GB HBM
// traffic per dispatch (ideal 52 MB), 527 us each. Replaced with MFMA GEMM:
//  - prep_weights: one-time dtype-convert + transpose of the 8 [128,128]
//    weight matrices to bf16 Wt[n][k] in ws (kills dual-dtype register bloat).
//  - gemm_nodes_mfma: 64 rows/block, mfma_f32_16x16x32_bf16, LDS +8 pad
//    (2-way bank aliasing only, which is free).
// Everything else unchanged from the passing round-3 kernel.
// ---------------------------------------------------------------------------

#define NN 50000
#define EE 600000
#define GG 256
#define HID 128
#define EDIM 16
#define EHID 64
#define NL 4
#define MIN_F 200
#define MH 256
#define MOUT 128
#define PH 512
#define PIN 256

typedef __hip_bfloat16 bf16;
typedef __attribute__((ext_vector_type(8))) short bf16x8;
typedef __attribute__((ext_vector_type(4))) float f32x4;

__device__ __forceinline__ float bfl(unsigned u) { return __uint_as_float(u << 16); }
__device__ __forceinline__ float bfh(unsigned u) { return __uint_as_float(u & 0xffff0000u); }
__device__ __forceinline__ float b2f(bf16 x) { return __bfloat162float(x); }
__device__ __forceinline__ float ldf(const void* p, long i, bool bf) {
  return bf ? __bfloat162float(((const bf16*)p)[i]) : ((const float*)p)[i];
}
__device__ __forceinline__ unsigned short f2bf_bits(float v) {
  bf16 h = __float2bfloat16(v);
  return *reinterpret_cast<unsigned short*>(&h);
}

// ---------------- dtype probe ------------------------------------------------
__global__ void probe_kernel(const unsigned short* __restrict__ xs, int* flag) {
  if (threadIdx.x == 0 && blockIdx.x == 0) {
    int sane = 0;
    for (int i = 0; i < 128; i++) {
      unsigned e = (xs[i] >> 7) & 0xFF;
      if (e >= 96 && e <= 159) sane++;
    }
    *flag = (sane >= 112) ? 1 : 0;  // 1 = bf16 inputs
  }
}

// ---------------- input -> f32 conversion (4 elems/thread) ------------------
__global__ __launch_bounds__(256) void cvt_any(const void* __restrict__ in,
                                               float* __restrict__ outp, int n4,
                                               const int* __restrict__ flag) {
  bool bf = *flag != 0;
  int i = blockIdx.x * 256 + threadIdx.x;
  if (i >= n4) return;
  float4 v;
  if (bf) {
    uint2 u = reinterpret_cast<const uint2*>(in)[i];
    v.x = bfl(u.x); v.y = bfh(u.x); v.z = bfl(u.y); v.w = bfh(u.y);
  } else {
    v = reinterpret_cast<const float4*>(in)[i];
  }
  reinterpret_cast<float4*>(outp)[i] = v;
}

// ---------------- weight prep: 8x[128,128] -> bf16 transposed Wt[n][k] ------
__global__ __launch_bounds__(256) void prep_weights(const void* __restrict__ lin_W,
                                                    const void* __restrict__ gW,
                                                    unsigned short* __restrict__ Wt,
                                                    const int* __restrict__ flag) {
  bool bf = *flag != 0;
  int idx = blockIdx.x * 256 + threadIdx.x;  // 0 .. 8*16384-1
  if (idx >= 8 * 16384) return;
  int mat = idx >> 14;
  int rem = idx & 16383;
  int n = rem >> 7, k = rem & 127;
  const void* src = (mat < 4) ? lin_W : gW;
  long srcIdx = (long)(mat & 3) * 16384 + (long)k * 128 + n;
  Wt[idx] = f2bf_bits(ldf(src, srcIdx, bf));
}

// ---------------- CSR build: histogram / scan / fill ------------------------
__global__ __launch_bounds__(256) void count_kernel(const int* __restrict__ ei,
                                                    int* __restrict__ cnt) {
  int e = blockIdx.x * 256 + threadIdx.x;
  if (e >= EE) return;
  int c = ei[EE + e];
  c = min(max(c, 0), NN - 1);
  atomicAdd(&cnt[c], 1);
}

__global__ __launch_bounds__(256) void scan_kernel(const int* __restrict__ cnt,
                                                   int* __restrict__ offs) {
  __shared__ int ssum[256];
  int tid = threadIdx.x;
  const int STRIP = (NN + 255) / 256;  // 196
  int s0 = tid * STRIP;
  int s1 = min(s0 + STRIP, NN);
  int sum = 0;
  for (int i = s0; i < s1; i++) sum += cnt[i];
  ssum[tid] = sum;
  __syncthreads();
  if (tid == 0) {
    int acc = 0;
    for (int i = 0; i < 256; i++) { int v = ssum[i]; ssum[i] = acc; acc += v; }
    offs[NN] = acc;
  }
  __syncthreads();
  int run = ssum[tid];
  for (int i = s0; i < s1; i++) { offs[i] = run; run += cnt[i]; }
}

__global__ __launch_bounds__(256) void fill_kernel(const int* __restrict__ ei,
                                                   const int* __restrict__ offs,
                                                   int* __restrict__ cursor,
                                                   int* __restrict__ csr_src,
                                                   int* __restrict__ csr_eid) {
  int e = blockIdx.x * 256 + threadIdx.x;
  if (e >= EE) return;
  int c = ei[EE + e];
  c = min(max(c, 0), NN - 1);
  int pos = offs[c] + atomicAdd(&cursor[c], 1);
  pos = min(max(pos, 0), EE - 1);
  csr_src[pos] = ei[e];
  csr_eid[pos] = e;
}

// ---------------- edge-gate MLP, all 4 layers, writes in CSR order ----------
__global__ __launch_bounds__(256) void edge_mlp_kernel(
    const void* __restrict__ eattr, const void* __restrict__ mW1,
    const void* __restrict__ mb1, const void* __restrict__ mW2,
    const void* __restrict__ mb2, const int* __restrict__ csr_eid,
    float* __restrict__ csr_val, const int* __restrict__ flag) {
  bool bf = *flag != 0;
  __shared__ alignas(16) float sW1[NL][EHID][EDIM];  // transposed: k contiguous
  __shared__ float sb1[NL][EHID];
  __shared__ float sW2[NL][EHID];
  __shared__ float sb2[NL];
  int tid = threadIdx.x;
  for (int i = tid; i < NL * EDIM * EHID; i += 256) {
    int l = i / (EDIM * EHID);
    int rem = i - l * (EDIM * EHID);
    int k = rem / EHID;
    int j = rem - k * EHID;
    sW1[l][j][k] = ldf(mW1, i, bf);
  }
  for (int i = tid; i < NL * EHID; i += 256) {
    sb1[i / EHID][i % EHID] = ldf(mb1, i, bf);
    sW2[i / EHID][i % EHID] = ldf(mW2, i, bf);
  }
  if (tid < NL) sb2[tid] = ldf(mb2, tid, bf);
  __syncthreads();

  int k0 = (blockIdx.x * 256 + tid) * 4;
  float attr[4][EDIM];
#pragma unroll
  for (int t = 0; t < 4; t++) {
    int k = k0 + t;
    if (k < EE) {
      long eid = csr_eid[k];
      if (bf) {
        const uint4* p = reinterpret_cast<const uint4*>((const bf16*)eattr + eid * EDIM);
        uint4 u0 = p[0], u1 = p[1];
        attr[t][0] = bfl(u0.x);  attr[t][1] = bfh(u0.x);
        attr[t][2] = bfl(u0.y);  attr[t][3] = bfh(u0.y);
        attr[t][4] = bfl(u0.z);  attr[t][5] = bfh(u0.z);
        attr[t][6] = bfl(u0.w);  attr[t][7] = bfh(u0.w);
        attr[t][8] = bfl(u1.x);  attr[t][9] = bfh(u1.x);
        attr[t][10] = bfl(u1.y); attr[t][11] = bfh(u1.y);
        attr[t][12] = bfl(u1.z); attr[t][13] = bfh(u1.z);
        attr[t][14] = bfl(u1.w); attr[t][15] = bfh(u1.w);
      } else {
        const float4* p = reinterpret_cast<const float4*>((const float*)eattr + eid * EDIM);
#pragma unroll
        for (int q = 0; q < 4; q++) {
          float4 v = p[q];
          attr[t][q * 4 + 0] = v.x; attr[t][q * 4 + 1] = v.y;
          attr[t][q * 4 + 2] = v.z; attr[t][q * 4 + 3] = v.w;
        }
      }
    } else {
#pragma unroll
      for (int k2 = 0; k2 < EDIM; k2++) attr[t][k2] = 0.f;
    }
  }

  for (int l = 0; l < NL; l++) {
    float acc[4];
#pragma unroll
    for (int t = 0; t < 4; t++) acc[t] = sb2[l];
    for (int j = 0; j < EHID; j++) {
      const float4* wp = reinterpret_cast<const float4*>(&sW1[l][j][0]);
      float4 a0 = wp[0], a1 = wp[1], a2 = wp[2], a3 = wp[3];
      float wk[EDIM] = {a0.x, a0.y, a0.z, a0.w, a1.x, a1.y, a1.z, a1.w,
                        a2.x, a2.y, a2.z, a2.w, a3.x, a3.y, a3.z, a3.w};
      float bj = sb1[l][j], w2 = sW2[l][j];
#pragma unroll
      for (int t = 0; t < 4; t++) {
        float s = bj;
#pragma unroll
        for (int k2 = 0; k2 < EDIM; k2++) s = fmaf(attr[t][k2], wk[k2], s);
        acc[t] += fmaxf(s, 0.f) * w2;
      }
    }
    float4 r;
    r.x = 1.f / (1.f + __expf(-acc[0]));
    r.y = 1.f / (1.f + __expf(-acc[1]));
    r.z = 1.f / (1.f + __expf(-acc[2]));
    r.w = 1.f / (1.f + __expf(-acc[3]));
    if (k0 + 4 <= EE) {
      *reinterpret_cast<float4*>(&csr_val[(size_t)l * EE + k0]) = r;
    } else {
      float rr[4] = {r.x, r.y, r.z, r.w};
      for (int t = 0; t < 4; t++)
        if (k0 + t < EE) csr_val[(size_t)l * EE + k0 + t] = rr[t];
    }
  }
}

// ---------------- degree / dinv per layer (contiguous csr_val reads) --------
__global__ __launch_bounds__(256) void deg_kernel(const int* __restrict__ offs,
                                                  const float* __restrict__ csr_val,
                                                  float* __restrict__ dinv_all) {
  int n = blockIdx.x * 256 + threadIdx.x;
  if (n >= NN) return;
  int s = offs[n], e = offs[n + 1];
  float d0 = 1.f, d1 = 1.f, d2 = 1.f, d3 = 1.f;  // self-loop weight 1.0
  for (int k = s; k < e; k++) {
    d0 += csr_val[k];
    d1 += csr_val[EE + k];
    d2 += csr_val[2 * (size_t)EE + k];
    d3 += csr_val[3 * (size_t)EE + k];
  }
  dinv_all[n] = rsqrtf(d0);
  dinv_all[NN + n] = rsqrtf(d1);
  dinv_all[2 * NN + n] = rsqrtf(d2);
  dinv_all[3 * NN + n] = rsqrtf(d3);
}

// csr_val[l][k] *= dinv_l[src_k]   (dinv[dst] factor applied in aggregate)
__global__ __launch_bounds__(256) void csr_scale_kernel(const int* __restrict__ csr_src,
                                                        const float* __restrict__ dinv_all,
                                                        float* __restrict__ csr_val) {
  int k = blockIdx.x * 256 + threadIdx.x;
  if (k >= EE) return;
  int s = csr_src[k];
  s = min(max(s, 0), NN - 1);
#pragma unroll
  for (int l = 0; l < NL; l++)
    csr_val[(size_t)l * EE + k] *= dinv_all[(size_t)l * NN + s];
}

// ---------------- node GEMM via MFMA ----------------------------------------
// out[N,128] = A[N,128](f32, rounded to bf16) @ W[128,128] (+bias)(+relu)
// Wt is bf16 transposed [n][k]. 64 rows/block, 4 waves, wave = 16-row strip.
__global__ __launch_bounds__(256) void gemm_nodes_mfma(
    const float* __restrict__ A, const unsigned short* __restrict__ Wt,
    const void* __restrict__ bias, long boff, float* __restrict__ outp,
    int relu, const int* __restrict__ flag) {
  __shared__ alignas(16) unsigned short sA[64 * 136];   // +8 pad: 2-way banks only
  __shared__ alignas(16) unsigned short sW[128 * 136];
  int tid = threadIdx.x;
  int rbase = blockIdx.x * 64;

  // stage Wt -> sW (b128 copies, conflict-free)
#pragma unroll
  for (int p = 0; p < 8; p++) {
    int idx8 = p * 256 + tid;        // 8-elem chunk id
    int n = idx8 >> 4, kc = idx8 & 15;
    uint4 v = reinterpret_cast<const uint4*>(Wt)[idx8];
    *reinterpret_cast<uint4*>(&sW[n * 136 + kc * 8]) = v;
  }
  // stage A rows f32 -> bf16 (coalesced float4 reads, b64 LDS writes)
#pragma unroll
  for (int p = 0; p < 8; p++) {
    int idx = p * 1024 + tid * 4;
    int m = idx >> 7, k = idx & 127;
    int row = rbase + m;
    float4 v = make_float4(0.f, 0.f, 0.f, 0.f);
    if (row < NN) v = *reinterpret_cast<const float4*>(&A[(size_t)row * HID + k]);
    ushort4 b;
    b.x = f2bf_bits(v.x); b.y = f2bf_bits(v.y);
    b.z = f2bf_bits(v.z); b.w = f2bf_bits(v.w);
    *reinterpret_cast<ushort4*>(&sA[m * 136 + k]) = b;
  }
  __syncthreads();

  int wave = tid >> 6, lane = tid & 63;
  int l15 = lane & 15, quad = lane >> 4;
  int mstrip = wave * 16;

  f32x4 acc[8];
#pragma unroll
  for (int t = 0; t < 8; t++) acc[t] = (f32x4){0.f, 0.f, 0.f, 0.f};

#pragma unroll
  for (int ks = 0; ks < 4; ks++) {
    int k0 = ks * 32 + quad * 8;
    bf16x8 a = *reinterpret_cast<const bf16x8*>(&sA[(mstrip + l15) * 136 + k0]);
#pragma unroll
    for (int t = 0; t < 8; t++) {
      bf16x8 b = *reinterpret_cast<const bf16x8*>(&sW[(t * 16 + l15) * 136 + k0]);
      acc[t] = __builtin_amdgcn_mfma_f32_16x16x32_bf16(a, b, acc[t], 0, 0, 0);
    }
  }

  bool bf = *flag != 0;
#pragma unroll
  for (int t = 0; t < 8; t++) {
    int n = t * 16 + l15;
    float bv = (boff >= 0) ? ldf(bias, boff + n, bf) : 0.f;
#pragma unroll
    for (int r = 0; r < 4; r++) {
      int row = rbase + mstrip + quad * 4 + r;
      if (row < NN) {
        float o = acc[t][r] + bv;
        if (relu) o = fmaxf(o, 0.f);
        outp[(size_t)row * HID + n] = o;
      }
    }
  }
}

// ---------------- aggregation ------------------------------------------------
// out[n] = dinv[n]*(sum_k val_k*hl[src_k]) + dinv[n]^2*hl[n] + bias
__global__ __launch_bounds__(128) void aggregate_kernel(const float* __restrict__ hl,
                                                        const int* __restrict__ offs,
                                                        const int* __restrict__ csr_src,
                                                        const float* __restrict__ csr_val,
                                                        const float* __restrict__ dinv,
                                                        const void* __restrict__ bias, long boff,
                                                        float* __restrict__ outp,
                                                        const int* __restrict__ flag) {
  bool bf = *flag != 0;
  int n = blockIdx.x;
  int c = threadIdx.x;
  __shared__ int s_src[128];
  __shared__ float s_val[128];
  int start = offs[n], end = offs[n + 1];
  float acc = 0.f;
  for (int base = start; base < end; base += 128) {
    int k = base + c;
    if (k < end) {
      int sr = csr_src[k];
      s_src[c] = min(max(sr, 0), NN - 1);
      s_val[c] = csr_val[k];
    }
    __syncthreads();
    int m = min(128, end - base);
    for (int j = 0; j < m; j++)
      acc = fmaf(s_val[j], hl[(size_t)s_src[j] * HID + c], acc);
    __syncthreads();
  }
  float dn = dinv[n];
  outp[(size_t)n * HID + c] =
      dn * acc + dn * dn * hl[(size_t)n * HID + c] + ldf(bias, boff + c, bf);
}

// ---------------- mean pool per graph (sorted batch_index) ------------------
__global__ __launch_bounds__(128) void pool_kernel(const float* __restrict__ h,
                                                   const int* __restrict__ batch,
                                                   float* __restrict__ cat) {
  int g = blockIdx.x, c = threadIdx.x;
  int lo = 0, hi = NN;
  while (lo < hi) { int mid = (lo + hi) >> 1; if (batch[mid] < g) lo = mid + 1; else hi = mid; }
  int start = lo;
  hi = NN;
  while (lo < hi) { int mid = (lo + hi) >> 1; if (batch[mid] < g + 1) lo = mid + 1; else hi = mid; }
  int end = lo;
  float s = 0.f;
  for (int n = start; n < end; n++) s += h[(size_t)n * HID + c];
  float cntf = (float)(end - start);
  cat[(size_t)g * PIN + c] = s / fmaxf(cntf, 1.f);
}

// ---------------- small dense GEMM (G rows) ---------------------------------
__global__ __launch_bounds__(256) void gemm_small(const float* __restrict__ A,
                                                  const void* __restrict__ W,
                                                  const void* __restrict__ bias,
                                                  float* __restrict__ outp, int M, int K,
                                                  int Nout, int out_ld, int relu,
                                                  const int* __restrict__ flag) {
  bool bf = *flag != 0;
  int idx = blockIdx.x * 256 + threadIdx.x;
  if (idx >= M * Nout) return;
  int row = idx / Nout, col = idx - row * Nout;
  const float* a = A + (size_t)row * K;
  float acc = ldf(bias, col, bf);
  for (int k = 0; k < K; k++) acc = fmaf(a[k], ldf(W, (long)k * Nout + col, bf), acc);
  if (relu) acc = fmaxf(acc, 0.f);
  outp[(size_t)row * out_ld + col] = acc;
}

// ---------------- final [G,512] @ [512,1] + b -> out (dtype per flag) -------
__global__ __launch_bounds__(64) void final_kernel(const float* __restrict__ A,
                                                   const void* __restrict__ W,
                                                   const void* __restrict__ b,
                                                   void* __restrict__ outp,
                                                   const int* __restrict__ flag) {
  bool bf = *flag != 0;
  int g = blockIdx.x, lane = threadIdx.x;
  float s = 0.f;
  for (int k = lane; k < PH; k += 64) s = fmaf(A[(size_t)g * PH + k], ldf(W, k, bf), s);
#pragma unroll
  for (int off = 32; off > 0; off >>= 1) s += __shfl_down(s, off);
  if (lane == 0) {
    float r = s + ldf(b, 0, bf);
    if (bf) ((bf16*)outp)[g] = __float2bfloat16(r);
    else    ((float*)outp)[g] = r;
  }
}

// ---------------------------------------------------------------------------
extern "C" void kernel_launch(void* const* d_in, const int* in_sizes, int n_in,
                              void* d_out, int out_size, void* d_ws, size_t ws_size,
                              hipStream_t stream) {
  const void* x      = d_in[0];
  const int*  ei     = (const int*)d_in[1];
  const void* eattr  = d_in[2];
  const int*  batch  = (const int*)d_in[3];
  const void* molf   = d_in[4];
  const void* lin_W  = d_in[5];
  const void* mW1    = d_in[6];
  const void* mb1    = d_in[7];
  const void* mW2    = d_in[8];
  const void* mb2    = d_in[9];
  const void* cbias  = d_in[10];
  const void* gW     = d_in[11];
  const void* gb     = d_in[12];
  const void* mlpW0  = d_in[13];
  const void* mlpb0  = d_in[14];
  const void* mlpW1  = d_in[15];
  const void* mlpb1  = d_in[16];
  const void* mlpW2  = d_in[17];
  const void* mlpb2  = d_in[18];
  const void* mlpW3  = d_in[19];
  const void* mlpb3  = d_in[20];
  const void* predW0 = d_in[21];
  const void* predb0 = d_in[22];
  const void* predW1 = d_in[23];
  const void* predb1 = d_in[24];
  const void* outW   = d_in[25];
  const void* outb   = d_in[26];

  char* base = (char*)d_ws;
  size_t off = 0;
  auto alloc = [&](size_t bytes) -> char* {
    char* p = base + off;
    off = (off + bytes + 255) & ~(size_t)255;
    return p;
  };
  float* bufA     = (float*)alloc((size_t)NN * HID * 4);
  float* bufB     = (float*)alloc((size_t)NN * HID * 4);
  float* dinv_all = (float*)alloc((size_t)NL * NN * 4);
  int*   cnt      = (int*)alloc((size_t)NN * 4);
  int*   offs     = (int*)alloc((size_t)(NN + 1) * 4);
  int*   cursor   = (int*)alloc((size_t)NN * 4);
  int*   csr_src  = (int*)alloc((size_t)EE * 4);
  int*   csr_eid  = (int*)alloc((size_t)EE * 4);
  float* csr_val  = (float*)alloc((size_t)NL * EE * 4);
  unsigned short* Wt = (unsigned short*)alloc((size_t)8 * HID * HID * 2);
  int*   flag     = (int*)alloc(256);
  float* molf32   = (float*)alloc((size_t)GG * MIN_F * 4);
  float* m0       = (float*)alloc((size_t)GG * MH * 4);
  float* m1       = (float*)alloc((size_t)GG * MH * 4);
  float* cat      = (float*)alloc((size_t)GG * PIN * 4);
  float* p0       = (float*)alloc((size_t)GG * PH * 4);
  float* p1       = (float*)alloc((size_t)GG * PH * 4);

  hipMemsetAsync(cnt, 0, (size_t)NN * 4, stream);
  hipMemsetAsync(cursor, 0, (size_t)NN * 4, stream);

  // dtype probe first — everything downstream branches on it
  probe_kernel<<<1, 64, 0, stream>>>((const unsigned short*)x, flag);

  // weight prep (transposed bf16 copies of the 8 node-GEMM weights)
  prep_weights<<<512, 256, 0, stream>>>(lin_W, gW, Wt, flag);

  // x -> f32
  {
    int n4 = NN * HID / 4;
    cvt_any<<<(n4 + 255) / 256, 256, 0, stream>>>(x, bufA, n4, flag);
  }
  // CSR build
  count_kernel<<<(EE + 255) / 256, 256, 0, stream>>>(ei, cnt);
  scan_kernel<<<1, 256, 0, stream>>>(cnt, offs);
  fill_kernel<<<(EE + 255) / 256, 256, 0, stream>>>(ei, offs, cursor, csr_src, csr_eid);
  // edge gates (CSR order), degrees, scaling
  edge_mlp_kernel<<<(EE + 1023) / 1024, 256, 0, stream>>>(eattr, mW1, mb1, mW2, mb2,
                                                          csr_eid, csr_val, flag);
  deg_kernel<<<(NN + 255) / 256, 256, 0, stream>>>(offs, csr_val, dinv_all);
  csr_scale_kernel<<<(EE + 255) / 256, 256, 0, stream>>>(csr_src, dinv_all, csr_val);

  // GCN layers
  float* h = bufA;
  float* t = bufB;
  const int gemm_blocks = (NN + 63) / 64;  // 782
  for (int l = 0; l < NL; l++) {
    gemm_nodes_mfma<<<gemm_blocks, 256, 0, stream>>>(
        h, Wt + (size_t)l * HID * HID, nullptr, -1, t, 0, flag);
    aggregate_kernel<<<NN, 128, 0, stream>>>(t, offs, csr_src, csr_val + (size_t)l * EE,
                                             dinv_all + (size_t)l * NN, cbias,
                                             (long)l * HID, h, flag);
    gemm_nodes_mfma<<<gemm_blocks, 256, 0, stream>>>(
        h, Wt + (size_t)(4 + l) * HID * HID, gb, (long)l * HID, t, 1, flag);
    float* tmp = h; h = t; t = tmp;
  }

  // pooling -> cat[:, 0:128]
  pool_kernel<<<GG, 128, 0, stream>>>(h, batch, cat);

  // molecular MLP -> cat[:, 128:256]
  {
    int n4 = GG * MIN_F / 4;
    cvt_any<<<(n4 + 255) / 256, 256, 0, stream>>>(molf, molf32, n4, flag);
  }
  gemm_small<<<(GG * MH + 255) / 256, 256, 0, stream>>>(molf32, mlpW0, mlpb0, m0, GG, MIN_F, MH, MH, 1, flag);
  gemm_small<<<(GG * MH + 255) / 256, 256, 0, stream>>>(m0, mlpW1, mlpb1, m1, GG, MH, MH, MH, 1, flag);
  gemm_small<<<(GG * MH + 255) / 256, 256, 0, stream>>>(m1, mlpW2, mlpb2, m0, GG, MH, MH, MH, 1, flag);
  gemm_small<<<(GG * MOUT + 255) / 256, 256, 0, stream>>>(m0, mlpW3, mlpb3, cat + MOUT, GG, MH, MOUT, PIN, 1, flag);

  // predictor
  gemm_small<<<(GG * PH + 255) / 256, 256, 0, stream>>>(cat, predW0, predb0, p0, GG, PIN, PH, PH, 1, flag);
  gemm_small<<<(GG * PH + 255) / 256, 256, 0, stream>>>(p0, predW1, predb1, p1, GG, PH, PH, PH, 1, flag);
  final_kernel<<<GG, 64, 0, stream>>>(p1, outW, outb, d_out, flag);
}

// Round 5
// 920.027 us; speedup vs baseline: 5.7776x; 1.6654x over previous
//
#include <hip/hip_runtime.h>
#include <hip/hip_bf16.h>

// ---------------------------------------------------------------------------
// PDNConv GNN, MI355X round 5.
// Round-4 profile: gemm_small (serial-K scalar loads, 1-2 waves/CU) cost
// 140-196 us x6 = ~950 us of 1532. Replaced the whole tail (mol MLP +
// predictor) with MFMA GEMMs over pre-transposed, K-padded bf16 weights.
// GCN core unchanged from round 4 (gemm_nodes_mfma + CSR aggregate).
// ---------------------------------------------------------------------------

#define NN 50000
#define EE 600000
#define GG 256
#define HID 128
#define EDIM 16
#define EHID 64
#define NL 4
#define MIN_F 200
#define MH 256
#define MOUT 128
#define PH 512
#define PIN 256

typedef __hip_bfloat16 bf16;
typedef __attribute__((ext_vector_type(8))) short bf16x8;
typedef __attribute__((ext_vector_type(4))) float f32x4;

__device__ __forceinline__ float bfl(unsigned u) { return __uint_as_float(u << 16); }
__device__ __forceinline__ float bfh(unsigned u) { return __uint_as_float(u & 0xffff0000u); }
__device__ __forceinline__ float b2f(bf16 x) { return __bfloat162float(x); }
__device__ __forceinline__ float ldf(const void* p, long i, bool bf) {
  return bf ? __bfloat162float(((const bf16*)p)[i]) : ((const float*)p)[i];
}
__device__ __forceinline__ unsigned short f2bf_bits(float v) {
  bf16 h = __float2bfloat16(v);
  return *reinterpret_cast<unsigned short*>(&h);
}

// ---------------- dtype probe ------------------------------------------------
__global__ void probe_kernel(const unsigned short* __restrict__ xs, int* flag) {
  if (threadIdx.x == 0 && blockIdx.x == 0) {
    int sane = 0;
    for (int i = 0; i < 128; i++) {
      unsigned e = (xs[i] >> 7) & 0xFF;
      if (e >= 96 && e <= 159) sane++;
    }
    *flag = (sane >= 112) ? 1 : 0;  // 1 = bf16 inputs
  }
}

// ---------------- input -> f32 conversion (4 elems/thread) ------------------
__global__ __launch_bounds__(256) void cvt_any(const void* __restrict__ in,
                                               float* __restrict__ outp, int n4,
                                               const int* __restrict__ flag) {
  bool bf = *flag != 0;
  int i = blockIdx.x * 256 + threadIdx.x;
  if (i >= n4) return;
  float4 v;
  if (bf) {
    uint2 u = reinterpret_cast<const uint2*>(in)[i];
    v.x = bfl(u.x); v.y = bfh(u.x); v.z = bfl(u.y); v.w = bfh(u.y);
  } else {
    v = reinterpret_cast<const float4*>(in)[i];
  }
  reinterpret_cast<float4*>(outp)[i] = v;
}

// ---------------- mol_features [G,200] -> padded f32 [G,256] ----------------
__global__ __launch_bounds__(256) void cvt_molf(const void* __restrict__ in,
                                                float* __restrict__ outp,
                                                const int* __restrict__ flag) {
  bool bf = *flag != 0;
  int i = blockIdx.x * 256 + threadIdx.x;  // GG*50
  if (i >= GG * 50) return;
  int row = i / 50, c4 = (i % 50) * 4;
  float4 v;
  if (bf) {
    const unsigned short* p = (const unsigned short*)in + (size_t)row * MIN_F + c4;
    uint2 u = *reinterpret_cast<const uint2*>(p);
    v.x = bfl(u.x); v.y = bfh(u.x); v.z = bfl(u.y); v.w = bfh(u.y);
  } else {
    v = *reinterpret_cast<const float4*>((const float*)in + (size_t)row * MIN_F + c4);
  }
  *reinterpret_cast<float4*>(&outp[(size_t)row * 256 + c4]) = v;
}

// ---------------- weight prep: node GEMM weights -> bf16 Wt[n][k] -----------
__global__ __launch_bounds__(256) void prep_weights(const void* __restrict__ lin_W,
                                                    const void* __restrict__ gW,
                                                    unsigned short* __restrict__ Wt,
                                                    const int* __restrict__ flag) {
  bool bf = *flag != 0;
  int idx = blockIdx.x * 256 + threadIdx.x;  // 0 .. 8*16384-1
  if (idx >= 8 * 16384) return;
  int mat = idx >> 14;
  int rem = idx & 16383;
  int n = rem >> 7, k = rem & 127;
  const void* src = (mat < 4) ? lin_W : gW;
  long srcIdx = (long)(mat & 3) * 16384 + (long)k * 128 + n;
  Wt[idx] = f2bf_bits(ldf(src, srcIdx, bf));
}

// ---------------- weight prep: tail (MLP+predictor) -> bf16 [N][Kp], K-pad --
// layout in T: W0t(256x256,Ks200)@0  W1t(256x256)@65536  W2t(256x256)@131072
//              W3t(128x256)@196608  P0t(512x256)@229376  P1t(512x512)@360448
__global__ __launch_bounds__(256) void prep_tail(
    const void* __restrict__ mlpW0, const void* __restrict__ mlpW1,
    const void* __restrict__ mlpW2, const void* __restrict__ mlpW3,
    const void* __restrict__ predW0, const void* __restrict__ predW1,
    unsigned short* __restrict__ T, const int* __restrict__ flag) {
  bool bf = *flag != 0;
  int idx = blockIdx.x * 256 + threadIdx.x;
  const void* src; int N, Kp, Ksrc, off;
  if      (idx < 65536)  { src = mlpW0;  N = 256; Kp = 256; Ksrc = 200; off = 0; }
  else if (idx < 131072) { src = mlpW1;  N = 256; Kp = 256; Ksrc = 256; off = 65536; }
  else if (idx < 196608) { src = mlpW2;  N = 256; Kp = 256; Ksrc = 256; off = 131072; }
  else if (idx < 229376) { src = mlpW3;  N = 128; Kp = 256; Ksrc = 256; off = 196608; }
  else if (idx < 360448) { src = predW0; N = 512; Kp = 256; Ksrc = 256; off = 229376; }
  else if (idx < 622592) { src = predW1; N = 512; Kp = 512; Ksrc = 512; off = 360448; }
  else return;
  int rem = idx - off;
  int n = rem / Kp, k = rem % Kp;
  float v = (k < Ksrc) ? ldf(src, (long)k * N + n, bf) : 0.f;
  T[idx] = f2bf_bits(v);
}

// ---------------- CSR build: histogram / scan / fill ------------------------
__global__ __launch_bounds__(256) void count_kernel(const int* __restrict__ ei,
                                                    int* __restrict__ cnt) {
  int e = blockIdx.x * 256 + threadIdx.x;
  if (e >= EE) return;
  int c = ei[EE + e];
  c = min(max(c, 0), NN - 1);
  atomicAdd(&cnt[c], 1);
}

__global__ __launch_bounds__(256) void scan_kernel(const int* __restrict__ cnt,
                                                   int* __restrict__ offs) {
  __shared__ int ssum[256];
  int tid = threadIdx.x;
  const int STRIP = (NN + 255) / 256;  // 196
  int s0 = tid * STRIP;
  int s1 = min(s0 + STRIP, NN);
  int sum = 0;
  for (int i = s0; i < s1; i++) sum += cnt[i];
  ssum[tid] = sum;
  __syncthreads();
  if (tid == 0) {
    int acc = 0;
    for (int i = 0; i < 256; i++) { int v = ssum[i]; ssum[i] = acc; acc += v; }
    offs[NN] = acc;
  }
  __syncthreads();
  int run = ssum[tid];
  for (int i = s0; i < s1; i++) { offs[i] = run; run += cnt[i]; }
}

__global__ __launch_bounds__(256) void fill_kernel(const int* __restrict__ ei,
                                                   const int* __restrict__ offs,
                                                   int* __restrict__ cursor,
                                                   int* __restrict__ csr_src,
                                                   int* __restrict__ csr_eid) {
  int e = blockIdx.x * 256 + threadIdx.x;
  if (e >= EE) return;
  int c = ei[EE + e];
  c = min(max(c, 0), NN - 1);
  int pos = offs[c] + atomicAdd(&cursor[c], 1);
  pos = min(max(pos, 0), EE - 1);
  csr_src[pos] = ei[e];
  csr_eid[pos] = e;
}

// ---------------- edge-gate MLP, all 4 layers, writes in CSR order ----------
__global__ __launch_bounds__(256) void edge_mlp_kernel(
    const void* __restrict__ eattr, const void* __restrict__ mW1,
    const void* __restrict__ mb1, const void* __restrict__ mW2,
    const void* __restrict__ mb2, const int* __restrict__ csr_eid,
    float* __restrict__ csr_val, const int* __restrict__ flag) {
  bool bf = *flag != 0;
  __shared__ alignas(16) float sW1[NL][EHID][EDIM];  // transposed: k contiguous
  __shared__ float sb1[NL][EHID];
  __shared__ float sW2[NL][EHID];
  __shared__ float sb2[NL];
  int tid = threadIdx.x;
  for (int i = tid; i < NL * EDIM * EHID; i += 256) {
    int l = i / (EDIM * EHID);
    int rem = i - l * (EDIM * EHID);
    int k = rem / EHID;
    int j = rem - k * EHID;
    sW1[l][j][k] = ldf(mW1, i, bf);
  }
  for (int i = tid; i < NL * EHID; i += 256) {
    sb1[i / EHID][i % EHID] = ldf(mb1, i, bf);
    sW2[i / EHID][i % EHID] = ldf(mW2, i, bf);
  }
  if (tid < NL) sb2[tid] = ldf(mb2, tid, bf);
  __syncthreads();

  int k0 = (blockIdx.x * 256 + tid) * 4;
  float attr[4][EDIM];
#pragma unroll
  for (int t = 0; t < 4; t++) {
    int k = k0 + t;
    if (k < EE) {
      long eid = csr_eid[k];
      if (bf) {
        const uint4* p = reinterpret_cast<const uint4*>((const bf16*)eattr + eid * EDIM);
        uint4 u0 = p[0], u1 = p[1];
        attr[t][0] = bfl(u0.x);  attr[t][1] = bfh(u0.x);
        attr[t][2] = bfl(u0.y);  attr[t][3] = bfh(u0.y);
        attr[t][4] = bfl(u0.z);  attr[t][5] = bfh(u0.z);
        attr[t][6] = bfl(u0.w);  attr[t][7] = bfh(u0.w);
        attr[t][8] = bfl(u1.x);  attr[t][9] = bfh(u1.x);
        attr[t][10] = bfl(u1.y); attr[t][11] = bfh(u1.y);
        attr[t][12] = bfl(u1.z); attr[t][13] = bfh(u1.z);
        attr[t][14] = bfl(u1.w); attr[t][15] = bfh(u1.w);
      } else {
        const float4* p = reinterpret_cast<const float4*>((const float*)eattr + eid * EDIM);
#pragma unroll
        for (int q = 0; q < 4; q++) {
          float4 v = p[q];
          attr[t][q * 4 + 0] = v.x; attr[t][q * 4 + 1] = v.y;
          attr[t][q * 4 + 2] = v.z; attr[t][q * 4 + 3] = v.w;
        }
      }
    } else {
#pragma unroll
      for (int k2 = 0; k2 < EDIM; k2++) attr[t][k2] = 0.f;
    }
  }

  for (int l = 0; l < NL; l++) {
    float acc[4];
#pragma unroll
    for (int t = 0; t < 4; t++) acc[t] = sb2[l];
    for (int j = 0; j < EHID; j++) {
      const float4* wp = reinterpret_cast<const float4*>(&sW1[l][j][0]);
      float4 a0 = wp[0], a1 = wp[1], a2 = wp[2], a3 = wp[3];
      float wk[EDIM] = {a0.x, a0.y, a0.z, a0.w, a1.x, a1.y, a1.z, a1.w,
                        a2.x, a2.y, a2.z, a2.w, a3.x, a3.y, a3.z, a3.w};
      float bj = sb1[l][j], w2 = sW2[l][j];
#pragma unroll
      for (int t = 0; t < 4; t++) {
        float s = bj;
#pragma unroll
        for (int k2 = 0; k2 < EDIM; k2++) s = fmaf(attr[t][k2], wk[k2], s);
        acc[t] += fmaxf(s, 0.f) * w2;
      }
    }
    float4 r;
    r.x = 1.f / (1.f + __expf(-acc[0]));
    r.y = 1.f / (1.f + __expf(-acc[1]));
    r.z = 1.f / (1.f + __expf(-acc[2]));
    r.w = 1.f / (1.f + __expf(-acc[3]));
    if (k0 + 4 <= EE) {
      *reinterpret_cast<float4*>(&csr_val[(size_t)l * EE + k0]) = r;
    } else {
      float rr[4] = {r.x, r.y, r.z, r.w};
      for (int t = 0; t < 4; t++)
        if (k0 + t < EE) csr_val[(size_t)l * EE + k0 + t] = rr[t];
    }
  }
}

// ---------------- degree / dinv per layer (contiguous csr_val reads) --------
__global__ __launch_bounds__(256) void deg_kernel(const int* __restrict__ offs,
                                                  const float* __restrict__ csr_val,
                                                  float* __restrict__ dinv_all) {
  int n = blockIdx.x * 256 + threadIdx.x;
  if (n >= NN) return;
  int s = offs[n], e = offs[n + 1];
  float d0 = 1.f, d1 = 1.f, d2 = 1.f, d3 = 1.f;  // self-loop weight 1.0
  for (int k = s; k < e; k++) {
    d0 += csr_val[k];
    d1 += csr_val[EE + k];
    d2 += csr_val[2 * (size_t)EE + k];
    d3 += csr_val[3 * (size_t)EE + k];
  }
  dinv_all[n] = rsqrtf(d0);
  dinv_all[NN + n] = rsqrtf(d1);
  dinv_all[2 * NN + n] = rsqrtf(d2);
  dinv_all[3 * NN + n] = rsqrtf(d3);
}

// csr_val[l][k] *= dinv_l[src_k]   (dinv[dst] factor applied in aggregate)
__global__ __launch_bounds__(256) void csr_scale_kernel(const int* __restrict__ csr_src,
                                                        const float* __restrict__ dinv_all,
                                                        float* __restrict__ csr_val) {
  int k = blockIdx.x * 256 + threadIdx.x;
  if (k >= EE) return;
  int s = csr_src[k];
  s = min(max(s, 0), NN - 1);
#pragma unroll
  for (int l = 0; l < NL; l++)
    csr_val[(size_t)l * EE + k] *= dinv_all[(size_t)l * NN + s];
}

// ---------------- node GEMM via MFMA ----------------------------------------
// out[N,128] = A[N,128](f32 -> bf16) @ Wt[n][k] (+bias)(+relu)
__global__ __launch_bounds__(256) void gemm_nodes_mfma(
    const float* __restrict__ A, const unsigned short* __restrict__ Wt,
    const void* __restrict__ bias, long boff, float* __restrict__ outp,
    int relu, const int* __restrict__ flag) {
  __shared__ alignas(16) unsigned short sA[64 * 136];   // +8 pad: 2-way banks only
  __shared__ alignas(16) unsigned short sW[128 * 136];
  int tid = threadIdx.x;
  int rbase = blockIdx.x * 64;

#pragma unroll
  for (int p = 0; p < 8; p++) {
    int idx8 = p * 256 + tid;
    int n = idx8 >> 4, kc = idx8 & 15;
    uint4 v = reinterpret_cast<const uint4*>(Wt)[idx8];
    *reinterpret_cast<uint4*>(&sW[n * 136 + kc * 8]) = v;
  }
#pragma unroll
  for (int p = 0; p < 8; p++) {
    int idx = p * 1024 + tid * 4;
    int m = idx >> 7, k = idx & 127;
    int row = rbase + m;
    float4 v = make_float4(0.f, 0.f, 0.f, 0.f);
    if (row < NN) v = *reinterpret_cast<const float4*>(&A[(size_t)row * HID + k]);
    ushort4 b;
    b.x = f2bf_bits(v.x); b.y = f2bf_bits(v.y);
    b.z = f2bf_bits(v.z); b.w = f2bf_bits(v.w);
    *reinterpret_cast<ushort4*>(&sA[m * 136 + k]) = b;
  }
  __syncthreads();

  int wave = tid >> 6, lane = tid & 63;
  int l15 = lane & 15, quad = lane >> 4;
  int mstrip = wave * 16;

  f32x4 acc[8];
#pragma unroll
  for (int t = 0; t < 8; t++) acc[t] = (f32x4){0.f, 0.f, 0.f, 0.f};

#pragma unroll
  for (int ks = 0; ks < 4; ks++) {
    int k0 = ks * 32 + quad * 8;
    bf16x8 a = *reinterpret_cast<const bf16x8*>(&sA[(mstrip + l15) * 136 + k0]);
#pragma unroll
    for (int t = 0; t < 8; t++) {
      bf16x8 b = *reinterpret_cast<const bf16x8*>(&sW[(t * 16 + l15) * 136 + k0]);
      acc[t] = __builtin_amdgcn_mfma_f32_16x16x32_bf16(a, b, acc[t], 0, 0, 0);
    }
  }

  bool bf = *flag != 0;
#pragma unroll
  for (int t = 0; t < 8; t++) {
    int n = t * 16 + l15;
    float bv = (boff >= 0) ? ldf(bias, boff + n, bf) : 0.f;
#pragma unroll
    for (int r = 0; r < 4; r++) {
      int row = rbase + mstrip + quad * 4 + r;
      if (row < NN) {
        float o = acc[t][r] + bv;
        if (relu) o = fmaxf(o, 0.f);
        outp[(size_t)row * HID + n] = o;
      }
    }
  }
}

// ---------------- tail GEMM via MFMA ----------------------------------------
// out[256,N] = A[256,Kp](f32 -> bf16) @ Wt[N][Kp] (+bias)(relu)
// 64x64 tile per block, K-chunks of 256. Kp % 256 == 0.
__global__ __launch_bounds__(256) void gemm_tail_mfma(
    const float* __restrict__ A, int lda, const unsigned short* __restrict__ Wt,
    int Kp, const void* __restrict__ bias, float* __restrict__ outp, int ldo,
    int relu, const int* __restrict__ flag) {
  __shared__ alignas(16) unsigned short sA[64 * 264];
  __shared__ alignas(16) unsigned short sW[64 * 264];
  int tid = threadIdx.x;
  int rbase = blockIdx.x * 64;
  int nbase = blockIdx.y * 64;
  int wave = tid >> 6, lane = tid & 63;
  int l15 = lane & 15, quad = lane >> 4;
  int mstrip = wave * 16;

  f32x4 acc[4];
#pragma unroll
  for (int t = 0; t < 4; t++) acc[t] = (f32x4){0.f, 0.f, 0.f, 0.f};

  for (int kc = 0; kc < Kp; kc += 256) {
    // stage A: 64 rows x 256 cols, f32 -> bf16
#pragma unroll 4
    for (int p = 0; p < 16; p++) {
      int idx = p * 1024 + tid * 4;
      int m = idx >> 8, k = idx & 255;
      float4 v = *reinterpret_cast<const float4*>(&A[(size_t)(rbase + m) * lda + kc + k]);
      ushort4 b;
      b.x = f2bf_bits(v.x); b.y = f2bf_bits(v.y);
      b.z = f2bf_bits(v.z); b.w = f2bf_bits(v.w);
      *reinterpret_cast<ushort4*>(&sA[m * 264 + k]) = b;
    }
    // stage Wt: 64 rows x 256 cols bf16
#pragma unroll 4
    for (int p = 0; p < 8; p++) {
      int idx8 = p * 256 + tid;
      int n = idx8 >> 5, kk = (idx8 & 31) * 8;
      uint4 v = *reinterpret_cast<const uint4*>(&Wt[(size_t)(nbase + n) * Kp + kc + kk]);
      *reinterpret_cast<uint4*>(&sW[n * 264 + kk]) = v;
    }
    __syncthreads();
#pragma unroll
    for (int ks = 0; ks < 8; ks++) {
      int k0 = ks * 32 + quad * 8;
      bf16x8 a = *reinterpret_cast<const bf16x8*>(&sA[(mstrip + l15) * 264 + k0]);
#pragma unroll
      for (int nt = 0; nt < 4; nt++) {
        bf16x8 b = *reinterpret_cast<const bf16x8*>(&sW[(nt * 16 + l15) * 264 + k0]);
        acc[nt] = __builtin_amdgcn_mfma_f32_16x16x32_bf16(a, b, acc[nt], 0, 0, 0);
      }
    }
    __syncthreads();
  }

  bool bf = *flag != 0;
#pragma unroll
  for (int nt = 0; nt < 4; nt++) {
    int col = nbase + nt * 16 + l15;
    float bv = ldf(bias, col, bf);
#pragma unroll
    for (int r = 0; r < 4; r++) {
      int row = rbase + mstrip + quad * 4 + r;
      float o = acc[nt][r] + bv;
      if (relu) o = fmaxf(o, 0.f);
      outp[(size_t)row * ldo + col] = o;
    }
  }
}

// ---------------- aggregation ------------------------------------------------
// out[n] = dinv[n]*(sum_k val_k*hl[src_k]) + dinv[n]^2*hl[n] + bias
__global__ __launch_bounds__(128) void aggregate_kernel(const float* __restrict__ hl,
                                                        const int* __restrict__ offs,
                                                        const int* __restrict__ csr_src,
                                                        const float* __restrict__ csr_val,
                                                        const float* __restrict__ dinv,
                                                        const void* __restrict__ bias, long boff,
                                                        float* __restrict__ outp,
                                                        const int* __restrict__ flag) {
  bool bf = *flag != 0;
  int n = blockIdx.x;
  int c = threadIdx.x;
  __shared__ int s_src[128];
  __shared__ float s_val[128];
  int start = offs[n], end = offs[n + 1];
  float acc = 0.f;
  for (int base = start; base < end; base += 128) {
    int k = base + c;
    if (k < end) {
      int sr = csr_src[k];
      s_src[c] = min(max(sr, 0), NN - 1);
      s_val[c] = csr_val[k];
    }
    __syncthreads();
    int m = min(128, end - base);
    for (int j = 0; j < m; j++)
      acc = fmaf(s_val[j], hl[(size_t)s_src[j] * HID + c], acc);
    __syncthreads();
  }
  float dn = dinv[n];
  outp[(size_t)n * HID + c] =
      dn * acc + dn * dn * hl[(size_t)n * HID + c] + ldf(bias, boff + c, bf);
}

// ---------------- mean pool per graph (sorted batch_index) ------------------
__global__ __launch_bounds__(128) void pool_kernel(const float* __restrict__ h,
                                                   const int* __restrict__ batch,
                                                   float* __restrict__ cat) {
  int g = blockIdx.x, c = threadIdx.x;
  int lo = 0, hi = NN;
  while (lo < hi) { int mid = (lo + hi) >> 1; if (batch[mid] < g) lo = mid + 1; else hi = mid; }
  int start = lo;
  hi = NN;
  while (lo < hi) { int mid = (lo + hi) >> 1; if (batch[mid] < g + 1) lo = mid + 1; else hi = mid; }
  int end = lo;
  float s = 0.f;
  for (int n = start; n < end; n++) s += h[(size_t)n * HID + c];
  float cntf = (float)(end - start);
  cat[(size_t)g * PIN + c] = s / fmaxf(cntf, 1.f);
}

// ---------------- final [G,512] @ [512,1] + b -> out (dtype per flag) -------
__global__ __launch_bounds__(64) void final_kernel(const float* __restrict__ A,
                                                   const void* __restrict__ W,
                                                   const void* __restrict__ b,
                                                   void* __restrict__ outp,
                                                   const int* __restrict__ flag) {
  bool bf = *flag != 0;
  int g = blockIdx.x, lane = threadIdx.x;
  float s = 0.f;
  for (int k = lane; k < PH; k += 64) s = fmaf(A[(size_t)g * PH + k], ldf(W, k, bf), s);
#pragma unroll
  for (int off = 32; off > 0; off >>= 1) s += __shfl_down(s, off);
  if (lane == 0) {
    float r = s + ldf(b, 0, bf);
    if (bf) ((bf16*)outp)[g] = __float2bfloat16(r);
    else    ((float*)outp)[g] = r;
  }
}

// ---------------------------------------------------------------------------
extern "C" void kernel_launch(void* const* d_in, const int* in_sizes, int n_in,
                              void* d_out, int out_size, void* d_ws, size_t ws_size,
                              hipStream_t stream) {
  const void* x      = d_in[0];
  const int*  ei     = (const int*)d_in[1];
  const void* eattr  = d_in[2];
  const int*  batch  = (const int*)d_in[3];
  const void* molf   = d_in[4];
  const void* lin_W  = d_in[5];
  const void* mW1    = d_in[6];
  const void* mb1    = d_in[7];
  const void* mW2    = d_in[8];
  const void* mb2    = d_in[9];
  const void* cbias  = d_in[10];
  const void* gW     = d_in[11];
  const void* gb     = d_in[12];
  const void* mlpW0  = d_in[13];
  const void* mlpb0  = d_in[14];
  const void* mlpW1  = d_in[15];
  const void* mlpb1  = d_in[16];
  const void* mlpW2  = d_in[17];
  const void* mlpb2  = d_in[18];
  const void* mlpW3  = d_in[19];
  const void* mlpb3  = d_in[20];
  const void* predW0 = d_in[21];
  const void* predb0 = d_in[22];
  const void* predW1 = d_in[23];
  const void* predb1 = d_in[24];
  const void* outW   = d_in[25];
  const void* outb   = d_in[26];

  char* base = (char*)d_ws;
  size_t off = 0;
  auto alloc = [&](size_t bytes) -> char* {
    char* p = base + off;
    off = (off + bytes + 255) & ~(size_t)255;
    return p;
  };
  float* bufA     = (float*)alloc((size_t)NN * HID * 4);
  float* bufB     = (float*)alloc((size_t)NN * HID * 4);
  float* dinv_all = (float*)alloc((size_t)NL * NN * 4);
  int*   cnt      = (int*)alloc((size_t)NN * 4);
  int*   offs     = (int*)alloc((size_t)(NN + 1) * 4);
  int*   cursor   = (int*)alloc((size_t)NN * 4);
  int*   csr_src  = (int*)alloc((size_t)EE * 4);
  int*   csr_eid  = (int*)alloc((size_t)EE * 4);
  float* csr_val  = (float*)alloc((size_t)NL * EE * 4);
  unsigned short* Wt   = (unsigned short*)alloc((size_t)8 * HID * HID * 2);
  unsigned short* tailW = (unsigned short*)alloc((size_t)622592 * 2);
  int*   flag     = (int*)alloc(256);
  float* molf32   = (float*)alloc((size_t)GG * 256 * 4);   // K-padded to 256
  float* m0       = (float*)alloc((size_t)GG * MH * 4);
  float* m1       = (float*)alloc((size_t)GG * MH * 4);
  float* cat      = (float*)alloc((size_t)GG * PIN * 4);
  float* p0       = (float*)alloc((size_t)GG * PH * 4);
  float* p1       = (float*)alloc((size_t)GG * PH * 4);

  hipMemsetAsync(cnt, 0, (size_t)NN * 4, stream);
  hipMemsetAsync(cursor, 0, (size_t)NN * 4, stream);
  hipMemsetAsync(molf32, 0, (size_t)GG * 256 * 4, stream);

  // dtype probe first — everything downstream branches on it
  probe_kernel<<<1, 64, 0, stream>>>((const unsigned short*)x, flag);

  // weight prep
  prep_weights<<<512, 256, 0, stream>>>(lin_W, gW, Wt, flag);
  prep_tail<<<(622592 + 255) / 256, 256, 0, stream>>>(mlpW0, mlpW1, mlpW2, mlpW3,
                                                      predW0, predW1, tailW, flag);

  // x -> f32
  {
    int n4 = NN * HID / 4;
    cvt_any<<<(n4 + 255) / 256, 256, 0, stream>>>(x, bufA, n4, flag);
  }
  // CSR build
  count_kernel<<<(EE + 255) / 256, 256, 0, stream>>>(ei, cnt);
  scan_kernel<<<1, 256, 0, stream>>>(cnt, offs);
  fill_kernel<<<(EE + 255) / 256, 256, 0, stream>>>(ei, offs, cursor, csr_src, csr_eid);
  // edge gates (CSR order), degrees, scaling
  edge_mlp_kernel<<<(EE + 1023) / 1024, 256, 0, stream>>>(eattr, mW1, mb1, mW2, mb2,
                                                          csr_eid, csr_val, flag);
  deg_kernel<<<(NN + 255) / 256, 256, 0, stream>>>(offs, csr_val, dinv_all);
  csr_scale_kernel<<<(EE + 255) / 256, 256, 0, stream>>>(csr_src, dinv_all, csr_val);

  // GCN layers
  float* h = bufA;
  float* t = bufB;
  const int gemm_blocks = (NN + 63) / 64;  // 782
  for (int l = 0; l < NL; l++) {
    gemm_nodes_mfma<<<gemm_blocks, 256, 0, stream>>>(
        h, Wt + (size_t)l * HID * HID, nullptr, -1, t, 0, flag);
    aggregate_kernel<<<NN, 128, 0, stream>>>(t, offs, csr_src, csr_val + (size_t)l * EE,
                                             dinv_all + (size_t)l * NN, cbias,
                                             (long)l * HID, h, flag);
    gemm_nodes_mfma<<<gemm_blocks, 256, 0, stream>>>(
        h, Wt + (size_t)(4 + l) * HID * HID, gb, (long)l * HID, t, 1, flag);
    float* tmp = h; h = t; t = tmp;
  }

  // pooling -> cat[:, 0:128]
  pool_kernel<<<GG, 128, 0, stream>>>(h, batch, cat);

  // molecular MLP -> cat[:, 128:256]  (MFMA tail, K-padded weights)
  cvt_molf<<<(GG * 50 + 255) / 256, 256, 0, stream>>>(molf, molf32, flag);
  gemm_tail_mfma<<<dim3(4, 4), 256, 0, stream>>>(molf32, 256, tailW + 0,      256, mlpb0, m0, 256, 1, flag);
  gemm_tail_mfma<<<dim3(4, 4), 256, 0, stream>>>(m0,     256, tailW + 65536,  256, mlpb1, m1, 256, 1, flag);
  gemm_tail_mfma<<<dim3(4, 4), 256, 0, stream>>>(m1,     256, tailW + 131072, 256, mlpb2, m0, 256, 1, flag);
  gemm_tail_mfma<<<dim3(4, 2), 256, 0, stream>>>(m0,     256, tailW + 196608, 256, mlpb3, cat + MOUT, 256, 1, flag);

  // predictor
  gemm_tail_mfma<<<dim3(4, 8), 256, 0, stream>>>(cat, 256, tailW + 229376, 256, predb0, p0, 512, 1, flag);
  gemm_tail_mfma<<<dim3(4, 8), 256, 0, stream>>>(p0,  512, tailW + 360448, 512, predb1, p1, 512, 1, flag);
  final_kernel<<<GG, 64, 0, stream>>>(p1, outW, outb, d_out, flag);
}

// Round 6
// 884.763 us; speedup vs baseline: 6.0079x; 1.0399x over previous
//
#include <hip/hip_runtime.h>
#include <hip/hip_bf16.h>

// ---------------------------------------------------------------------------
// PDNConv GNN, MI355X round 6.
// Round-5 profile: edge_mlp_kernel (scalar f32 MLP, VALUBusy 64%, VGPR 48)
// was #1 at 115 us. Replaced with MFMA: all 4 layers' [16,64] W1 fused into
// one bf16 [256][32] (K zero-padded), one K=32 MFMA shot per wave covers all
// hidden units; relu*w2 reduce via shfl_xor; sigmoid; write CSR-ordered.
// Everything else unchanged from round 5.
// ---------------------------------------------------------------------------

#define NN 50000
#define EE 600000
#define GG 256
#define HID 128
#define EDIM 16
#define EHID 64
#define NL 4
#define MIN_F 200
#define MH 256
#define MOUT 128
#define PH 512
#define PIN 256

typedef __hip_bfloat16 bf16;
typedef __attribute__((ext_vector_type(8))) short bf16x8;
typedef __attribute__((ext_vector_type(4))) float f32x4;

__device__ __forceinline__ float bfl(unsigned u) { return __uint_as_float(u << 16); }
__device__ __forceinline__ float bfh(unsigned u) { return __uint_as_float(u & 0xffff0000u); }
__device__ __forceinline__ float b2f(bf16 x) { return __bfloat162float(x); }
__device__ __forceinline__ float ldf(const void* p, long i, bool bf) {
  return bf ? __bfloat162float(((const bf16*)p)[i]) : ((const float*)p)[i];
}
__device__ __forceinline__ unsigned short f2bf_bits(float v) {
  bf16 h = __float2bfloat16(v);
  return *reinterpret_cast<unsigned short*>(&h);
}

// ---------------- dtype probe ------------------------------------------------
__global__ void probe_kernel(const unsigned short* __restrict__ xs, int* flag) {
  if (threadIdx.x == 0 && blockIdx.x == 0) {
    int sane = 0;
    for (int i = 0; i < 128; i++) {
      unsigned e = (xs[i] >> 7) & 0xFF;
      if (e >= 96 && e <= 159) sane++;
    }
    *flag = (sane >= 112) ? 1 : 0;  // 1 = bf16 inputs
  }
}

// ---------------- input -> f32 conversion (4 elems/thread) ------------------
__global__ __launch_bounds__(256) void cvt_any(const void* __restrict__ in,
                                               float* __restrict__ outp, int n4,
                                               const int* __restrict__ flag) {
  bool bf = *flag != 0;
  int i = blockIdx.x * 256 + threadIdx.x;
  if (i >= n4) return;
  float4 v;
  if (bf) {
    uint2 u = reinterpret_cast<const uint2*>(in)[i];
    v.x = bfl(u.x); v.y = bfh(u.x); v.z = bfl(u.y); v.w = bfh(u.y);
  } else {
    v = reinterpret_cast<const float4*>(in)[i];
  }
  reinterpret_cast<float4*>(outp)[i] = v;
}

// ---------------- mol_features [G,200] -> padded f32 [G,256] ----------------
__global__ __launch_bounds__(256) void cvt_molf(const void* __restrict__ in,
                                                float* __restrict__ outp,
                                                const int* __restrict__ flag) {
  bool bf = *flag != 0;
  int i = blockIdx.x * 256 + threadIdx.x;  // GG*50
  if (i >= GG * 50) return;
  int row = i / 50, c4 = (i % 50) * 4;
  float4 v;
  if (bf) {
    const unsigned short* p = (const unsigned short*)in + (size_t)row * MIN_F + c4;
    uint2 u = *reinterpret_cast<const uint2*>(p);
    v.x = bfl(u.x); v.y = bfh(u.x); v.z = bfl(u.y); v.w = bfh(u.y);
  } else {
    v = *reinterpret_cast<const float4*>((const float*)in + (size_t)row * MIN_F + c4);
  }
  *reinterpret_cast<float4*>(&outp[(size_t)row * 256 + c4]) = v;
}

// ---------------- weight prep: node GEMM weights -> bf16 Wt[n][k] -----------
__global__ __launch_bounds__(256) void prep_weights(const void* __restrict__ lin_W,
                                                    const void* __restrict__ gW,
                                                    unsigned short* __restrict__ Wt,
                                                    const int* __restrict__ flag) {
  bool bf = *flag != 0;
  int idx = blockIdx.x * 256 + threadIdx.x;  // 0 .. 8*16384-1
  if (idx >= 8 * 16384) return;
  int mat = idx >> 14;
  int rem = idx & 16383;
  int n = rem >> 7, k = rem & 127;
  const void* src = (mat < 4) ? lin_W : gW;
  long srcIdx = (long)(mat & 3) * 16384 + (long)k * 128 + n;
  Wt[idx] = f2bf_bits(ldf(src, srcIdx, bf));
}

// ---------------- weight prep: edge MLP W1 -> bf16 W1t[256 cols][32 K] ------
// col = l*64 + j ; K 16 zero-padded to 32. mW1 layout [NL][EDIM][EHID].
__global__ __launch_bounds__(256) void prep_edge_w(const void* __restrict__ mW1,
                                                   unsigned short* __restrict__ W1t,
                                                   const int* __restrict__ flag) {
  bool bf = *flag != 0;
  int idx = blockIdx.x * 256 + threadIdx.x;  // 256*32
  if (idx >= 256 * 32) return;
  int col = idx >> 5, k = idx & 31;
  float v = 0.f;
  if (k < EDIM) v = ldf(mW1, (long)(col >> 6) * (EDIM * EHID) + (long)k * EHID + (col & 63), bf);
  W1t[idx] = f2bf_bits(v);
}

// ---------------- weight prep: tail (MLP+predictor) -> bf16 [N][Kp], K-pad --
__global__ __launch_bounds__(256) void prep_tail(
    const void* __restrict__ mlpW0, const void* __restrict__ mlpW1,
    const void* __restrict__ mlpW2, const void* __restrict__ mlpW3,
    const void* __restrict__ predW0, const void* __restrict__ predW1,
    unsigned short* __restrict__ T, const int* __restrict__ flag) {
  bool bf = *flag != 0;
  int idx = blockIdx.x * 256 + threadIdx.x;
  const void* src; int N, Kp, Ksrc, off;
  if      (idx < 65536)  { src = mlpW0;  N = 256; Kp = 256; Ksrc = 200; off = 0; }
  else if (idx < 131072) { src = mlpW1;  N = 256; Kp = 256; Ksrc = 256; off = 65536; }
  else if (idx < 196608) { src = mlpW2;  N = 256; Kp = 256; Ksrc = 256; off = 131072; }
  else if (idx < 229376) { src = mlpW3;  N = 128; Kp = 256; Ksrc = 256; off = 196608; }
  else if (idx < 360448) { src = predW0; N = 512; Kp = 256; Ksrc = 256; off = 229376; }
  else if (idx < 622592) { src = predW1; N = 512; Kp = 512; Ksrc = 512; off = 360448; }
  else return;
  int rem = idx - off;
  int n = rem / Kp, k = rem % Kp;
  float v = (k < Ksrc) ? ldf(src, (long)k * N + n, bf) : 0.f;
  T[idx] = f2bf_bits(v);
}

// ---------------- CSR build: histogram / scan / fill ------------------------
__global__ __launch_bounds__(256) void count_kernel(const int* __restrict__ ei,
                                                    int* __restrict__ cnt) {
  int e = blockIdx.x * 256 + threadIdx.x;
  if (e >= EE) return;
  int c = ei[EE + e];
  c = min(max(c, 0), NN - 1);
  atomicAdd(&cnt[c], 1);
}

__global__ __launch_bounds__(256) void scan_kernel(const int* __restrict__ cnt,
                                                   int* __restrict__ offs) {
  __shared__ int ssum[256];
  int tid = threadIdx.x;
  const int STRIP = (NN + 255) / 256;  // 196
  int s0 = tid * STRIP;
  int s1 = min(s0 + STRIP, NN);
  int sum = 0;
  for (int i = s0; i < s1; i++) sum += cnt[i];
  ssum[tid] = sum;
  __syncthreads();
  if (tid == 0) {
    int acc = 0;
    for (int i = 0; i < 256; i++) { int v = ssum[i]; ssum[i] = acc; acc += v; }
    offs[NN] = acc;
  }
  __syncthreads();
  int run = ssum[tid];
  for (int i = s0; i < s1; i++) { offs[i] = run; run += cnt[i]; }
}

__global__ __launch_bounds__(256) void fill_kernel(const int* __restrict__ ei,
                                                   const int* __restrict__ offs,
                                                   int* __restrict__ cursor,
                                                   int* __restrict__ csr_src,
                                                   int* __restrict__ csr_eid) {
  int e = blockIdx.x * 256 + threadIdx.x;
  if (e >= EE) return;
  int c = ei[EE + e];
  c = min(max(c, 0), NN - 1);
  int pos = offs[c] + atomicAdd(&cursor[c], 1);
  pos = min(max(pos, 0), EE - 1);
  csr_src[pos] = ei[e];
  csr_eid[pos] = e;
}

// ---------------- edge-gate MLP via MFMA (all 4 layers, CSR order) ----------
// csr_val[l*EE + k] = sigmoid(relu(attr[eid_k] @ W1_l + b1_l) @ w2_l + b2_l)
// Block: 64 edges. One K=32 MFMA shot covers all 256 hidden units.
__global__ __launch_bounds__(256) void edge_mlp_mfma(
    const void* __restrict__ eattr, const unsigned short* __restrict__ W1t,
    const void* __restrict__ mb1, const void* __restrict__ mW2,
    const void* __restrict__ mb2, const int* __restrict__ csr_eid,
    float* __restrict__ csr_val, const int* __restrict__ flag) {
  bool bf = *flag != 0;
  __shared__ alignas(16) unsigned short sW[256 * 40];  // dword-stride 20: even banks
  __shared__ alignas(16) unsigned short sA[64 * 40];
  __shared__ float sb1f[256];
  __shared__ float sw2f[256];
  __shared__ float sb2f[NL];
  int tid = threadIdx.x;
  int rbase = blockIdx.x * 64;

  // stage W1t (256x32 bf16 = 1024 uint4)
#pragma unroll
  for (int p = 0; p < 4; p++) {
    int idx8 = p * 256 + tid;
    int n = idx8 >> 2, kc = (idx8 & 3) * 8;
    uint4 v = reinterpret_cast<const uint4*>(W1t)[idx8];
    *reinterpret_cast<uint4*>(&sW[n * 40 + kc]) = v;
  }
  sb1f[tid] = ldf(mb1, tid, bf);   // mb1/mW2 are [NL][EHID] flat == col order
  sw2f[tid] = ldf(mW2, tid, bf);
  if (tid < NL) sb2f[tid] = ldf(mb2, tid, bf);

  // zero the K pad 16..31 (64 edges x 16 elems = 256 x ushort4)
  {
    int e = tid >> 2, q = tid & 3;
    ushort4 z; z.x = 0; z.y = 0; z.z = 0; z.w = 0;
    *reinterpret_cast<ushort4*>(&sA[e * 40 + 16 + q * 4]) = z;
  }
  // gather attr rows by csr_eid
  if (bf) {
    if (tid < 128) {
      int e = tid >> 1, half = tid & 1;
      long eid = csr_eid[rbase + e];
      uint4 v = reinterpret_cast<const uint4*>((const bf16*)eattr + eid * EDIM)[half];
      *reinterpret_cast<uint4*>(&sA[e * 40 + half * 8]) = v;
    }
  } else {
    int e = tid >> 2, q = tid & 3;
    long eid = csr_eid[rbase + e];
    float4 v = reinterpret_cast<const float4*>((const float*)eattr + eid * EDIM)[q];
    ushort4 b;
    b.x = f2bf_bits(v.x); b.y = f2bf_bits(v.y);
    b.z = f2bf_bits(v.z); b.w = f2bf_bits(v.w);
    *reinterpret_cast<ushort4*>(&sA[e * 40 + q * 4]) = b;
  }
  __syncthreads();

  int wave = tid >> 6, lane = tid & 63;
  int l15 = lane & 15, quad = lane >> 4;
  int mstrip = wave * 16;

  bf16x8 a = *reinterpret_cast<const bf16x8*>(&sA[(mstrip + l15) * 40 + quad * 8]);
  f32x4 acc[16];
#pragma unroll
  for (int t = 0; t < 16; t++) {
    bf16x8 b = *reinterpret_cast<const bf16x8*>(&sW[(t * 16 + l15) * 40 + quad * 8]);
    acc[t] = __builtin_amdgcn_mfma_f32_16x16x32_bf16(a, b, (f32x4){0.f, 0.f, 0.f, 0.f},
                                                     0, 0, 0);
  }

  // stage 2: s[l][r] = sum over 64 hidden units (4 t-tiles x 16 lanes)
  float s[NL][4];
#pragma unroll
  for (int l = 0; l < NL; l++) {
#pragma unroll
    for (int r = 0; r < 4; r++) s[l][r] = 0.f;
#pragma unroll
    for (int tt = 0; tt < 4; tt++) {
      int t = l * 4 + tt;
      int col = t * 16 + l15;
      float b1v = sb1f[col], w2v = sw2f[col];
#pragma unroll
      for (int r = 0; r < 4; r++)
        s[l][r] += fmaxf(acc[t][r] + b1v, 0.f) * w2v;
    }
  }
#pragma unroll
  for (int m = 1; m <= 8; m <<= 1) {
#pragma unroll
    for (int l = 0; l < NL; l++)
#pragma unroll
      for (int r = 0; r < 4; r++) s[l][r] += __shfl_xor(s[l][r], m);
  }
  if (l15 < NL) {
    int l = l15;
    float b2v = sb2f[l];
#pragma unroll
    for (int r = 0; r < 4; r++) {
      int e = rbase + mstrip + quad * 4 + r;
      csr_val[(size_t)l * EE + e] = 1.f / (1.f + __expf(-(s[l][r] + b2v)));
    }
  }
}

// ---------------- degree / dinv per layer (contiguous csr_val reads) --------
__global__ __launch_bounds__(256) void deg_kernel(const int* __restrict__ offs,
                                                  const float* __restrict__ csr_val,
                                                  float* __restrict__ dinv_all) {
  int n = blockIdx.x * 256 + threadIdx.x;
  if (n >= NN) return;
  int s = offs[n], e = offs[n + 1];
  float d0 = 1.f, d1 = 1.f, d2 = 1.f, d3 = 1.f;  // self-loop weight 1.0
  for (int k = s; k < e; k++) {
    d0 += csr_val[k];
    d1 += csr_val[EE + k];
    d2 += csr_val[2 * (size_t)EE + k];
    d3 += csr_val[3 * (size_t)EE + k];
  }
  dinv_all[n] = rsqrtf(d0);
  dinv_all[NN + n] = rsqrtf(d1);
  dinv_all[2 * NN + n] = rsqrtf(d2);
  dinv_all[3 * NN + n] = rsqrtf(d3);
}

// csr_val[l][k] *= dinv_l[src_k]   (dinv[dst] factor applied in aggregate)
__global__ __launch_bounds__(256) void csr_scale_kernel(const int* __restrict__ csr_src,
                                                        const float* __restrict__ dinv_all,
                                                        float* __restrict__ csr_val) {
  int k = blockIdx.x * 256 + threadIdx.x;
  if (k >= EE) return;
  int s = csr_src[k];
  s = min(max(s, 0), NN - 1);
#pragma unroll
  for (int l = 0; l < NL; l++)
    csr_val[(size_t)l * EE + k] *= dinv_all[(size_t)l * NN + s];
}

// ---------------- node GEMM via MFMA ----------------------------------------
__global__ __launch_bounds__(256) void gemm_nodes_mfma(
    const float* __restrict__ A, const unsigned short* __restrict__ Wt,
    const void* __restrict__ bias, long boff, float* __restrict__ outp,
    int relu, const int* __restrict__ flag) {
  __shared__ alignas(16) unsigned short sA[64 * 136];
  __shared__ alignas(16) unsigned short sW[128 * 136];
  int tid = threadIdx.x;
  int rbase = blockIdx.x * 64;

#pragma unroll
  for (int p = 0; p < 8; p++) {
    int idx8 = p * 256 + tid;
    int n = idx8 >> 4, kc = idx8 & 15;
    uint4 v = reinterpret_cast<const uint4*>(Wt)[idx8];
    *reinterpret_cast<uint4*>(&sW[n * 136 + kc * 8]) = v;
  }
#pragma unroll
  for (int p = 0; p < 8; p++) {
    int idx = p * 1024 + tid * 4;
    int m = idx >> 7, k = idx & 127;
    int row = rbase + m;
    float4 v = make_float4(0.f, 0.f, 0.f, 0.f);
    if (row < NN) v = *reinterpret_cast<const float4*>(&A[(size_t)row * HID + k]);
    ushort4 b;
    b.x = f2bf_bits(v.x); b.y = f2bf_bits(v.y);
    b.z = f2bf_bits(v.z); b.w = f2bf_bits(v.w);
    *reinterpret_cast<ushort4*>(&sA[m * 136 + k]) = b;
  }
  __syncthreads();

  int wave = tid >> 6, lane = tid & 63;
  int l15 = lane & 15, quad = lane >> 4;
  int mstrip = wave * 16;

  f32x4 acc[8];
#pragma unroll
  for (int t = 0; t < 8; t++) acc[t] = (f32x4){0.f, 0.f, 0.f, 0.f};

#pragma unroll
  for (int ks = 0; ks < 4; ks++) {
    int k0 = ks * 32 + quad * 8;
    bf16x8 a = *reinterpret_cast<const bf16x8*>(&sA[(mstrip + l15) * 136 + k0]);
#pragma unroll
    for (int t = 0; t < 8; t++) {
      bf16x8 b = *reinterpret_cast<const bf16x8*>(&sW[(t * 16 + l15) * 136 + k0]);
      acc[t] = __builtin_amdgcn_mfma_f32_16x16x32_bf16(a, b, acc[t], 0, 0, 0);
    }
  }

  bool bf = *flag != 0;
#pragma unroll
  for (int t = 0; t < 8; t++) {
    int n = t * 16 + l15;
    float bv = (boff >= 0) ? ldf(bias, boff + n, bf) : 0.f;
#pragma unroll
    for (int r = 0; r < 4; r++) {
      int row = rbase + mstrip + quad * 4 + r;
      if (row < NN) {
        float o = acc[t][r] + bv;
        if (relu) o = fmaxf(o, 0.f);
        outp[(size_t)row * HID + n] = o;
      }
    }
  }
}

// ---------------- tail GEMM via MFMA ----------------------------------------
__global__ __launch_bounds__(256) void gemm_tail_mfma(
    const float* __restrict__ A, int lda, const unsigned short* __restrict__ Wt,
    int Kp, const void* __restrict__ bias, float* __restrict__ outp, int ldo,
    int relu, const int* __restrict__ flag) {
  __shared__ alignas(16) unsigned short sA[64 * 264];
  __shared__ alignas(16) unsigned short sW[64 * 264];
  int tid = threadIdx.x;
  int rbase = blockIdx.x * 64;
  int nbase = blockIdx.y * 64;
  int wave = tid >> 6, lane = tid & 63;
  int l15 = lane & 15, quad = lane >> 4;
  int mstrip = wave * 16;

  f32x4 acc[4];
#pragma unroll
  for (int t = 0; t < 4; t++) acc[t] = (f32x4){0.f, 0.f, 0.f, 0.f};

  for (int kc = 0; kc < Kp; kc += 256) {
#pragma unroll 4
    for (int p = 0; p < 16; p++) {
      int idx = p * 1024 + tid * 4;
      int m = idx >> 8, k = idx & 255;
      float4 v = *reinterpret_cast<const float4*>(&A[(size_t)(rbase + m) * lda + kc + k]);
      ushort4 b;
      b.x = f2bf_bits(v.x); b.y = f2bf_bits(v.y);
      b.z = f2bf_bits(v.z); b.w = f2bf_bits(v.w);
      *reinterpret_cast<ushort4*>(&sA[m * 264 + k]) = b;
    }
#pragma unroll 4
    for (int p = 0; p < 8; p++) {
      int idx8 = p * 256 + tid;
      int n = idx8 >> 5, kk = (idx8 & 31) * 8;
      uint4 v = *reinterpret_cast<const uint4*>(&Wt[(size_t)(nbase + n) * Kp + kc + kk]);
      *reinterpret_cast<uint4*>(&sW[n * 264 + kk]) = v;
    }
    __syncthreads();
#pragma unroll
    for (int ks = 0; ks < 8; ks++) {
      int k0 = ks * 32 + quad * 8;
      bf16x8 a = *reinterpret_cast<const bf16x8*>(&sA[(mstrip + l15) * 264 + k0]);
#pragma unroll
      for (int nt = 0; nt < 4; nt++) {
        bf16x8 b = *reinterpret_cast<const bf16x8*>(&sW[(nt * 16 + l15) * 264 + k0]);
        acc[nt] = __builtin_amdgcn_mfma_f32_16x16x32_bf16(a, b, acc[nt], 0, 0, 0);
      }
    }
    __syncthreads();
  }

  bool bf = *flag != 0;
#pragma unroll
  for (int nt = 0; nt < 4; nt++) {
    int col = nbase + nt * 16 + l15;
    float bv = ldf(bias, col, bf);
#pragma unroll
    for (int r = 0; r < 4; r++) {
      int row = rbase + mstrip + quad * 4 + r;
      float o = acc[nt][r] + bv;
      if (relu) o = fmaxf(o, 0.f);
      outp[(size_t)row * ldo + col] = o;
    }
  }
}

// ---------------- aggregation ------------------------------------------------
// out[n] = dinv[n]*(sum_k val_k*hl[src_k]) + dinv[n]^2*hl[n] + bias
__global__ __launch_bounds__(128) void aggregate_kernel(const float* __restrict__ hl,
                                                        const int* __restrict__ offs,
                                                        const int* __restrict__ csr_src,
                                                        const float* __restrict__ csr_val,
                                                        const float* __restrict__ dinv,
                                                        const void* __restrict__ bias, long boff,
                                                        float* __restrict__ outp,
                                                        const int* __restrict__ flag) {
  bool bf = *flag != 0;
  int n = blockIdx.x;
  int c = threadIdx.x;
  __shared__ int s_src[128];
  __shared__ float s_val[128];
  int start = offs[n], end = offs[n + 1];
  float acc = 0.f;
  for (int base = start; base < end; base += 128) {
    int k = base + c;
    if (k < end) {
      int sr = csr_src[k];
      s_src[c] = min(max(sr, 0), NN - 1);
      s_val[c] = csr_val[k];
    }
    __syncthreads();
    int m = min(128, end - base);
    for (int j = 0; j < m; j++)
      acc = fmaf(s_val[j], hl[(size_t)s_src[j] * HID + c], acc);
    __syncthreads();
  }
  float dn = dinv[n];
  outp[(size_t)n * HID + c] =
      dn * acc + dn * dn * hl[(size_t)n * HID + c] + ldf(bias, boff + c, bf);
}

// ---------------- mean pool per graph (sorted batch_index) ------------------
__global__ __launch_bounds__(128) void pool_kernel(const float* __restrict__ h,
                                                   const int* __restrict__ batch,
                                                   float* __restrict__ cat) {
  int g = blockIdx.x, c = threadIdx.x;
  int lo = 0, hi = NN;
  while (lo < hi) { int mid = (lo + hi) >> 1; if (batch[mid] < g) lo = mid + 1; else hi = mid; }
  int start = lo;
  hi = NN;
  while (lo < hi) { int mid = (lo + hi) >> 1; if (batch[mid] < g + 1) lo = mid + 1; else hi = mid; }
  int end = lo;
  float s = 0.f;
  for (int n = start; n < end; n++) s += h[(size_t)n * HID + c];
  float cntf = (float)(end - start);
  cat[(size_t)g * PIN + c] = s / fmaxf(cntf, 1.f);
}

// ---------------- final [G,512] @ [512,1] + b -> out (dtype per flag) -------
__global__ __launch_bounds__(64) void final_kernel(const float* __restrict__ A,
                                                   const void* __restrict__ W,
                                                   const void* __restrict__ b,
                                                   void* __restrict__ outp,
                                                   const int* __restrict__ flag) {
  bool bf = *flag != 0;
  int g = blockIdx.x, lane = threadIdx.x;
  float s = 0.f;
  for (int k = lane; k < PH; k += 64) s = fmaf(A[(size_t)g * PH + k], ldf(W, k, bf), s);
#pragma unroll
  for (int off = 32; off > 0; off >>= 1) s += __shfl_down(s, off);
  if (lane == 0) {
    float r = s + ldf(b, 0, bf);
    if (bf) ((bf16*)outp)[g] = __float2bfloat16(r);
    else    ((float*)outp)[g] = r;
  }
}

// ---------------------------------------------------------------------------
extern "C" void kernel_launch(void* const* d_in, const int* in_sizes, int n_in,
                              void* d_out, int out_size, void* d_ws, size_t ws_size,
                              hipStream_t stream) {
  const void* x      = d_in[0];
  const int*  ei     = (const int*)d_in[1];
  const void* eattr  = d_in[2];
  const int*  batch  = (const int*)d_in[3];
  const void* molf   = d_in[4];
  const void* lin_W  = d_in[5];
  const void* mW1    = d_in[6];
  const void* mb1    = d_in[7];
  const void* mW2    = d_in[8];
  const void* mb2    = d_in[9];
  const void* cbias  = d_in[10];
  const void* gW     = d_in[11];
  const void* gb     = d_in[12];
  const void* mlpW0  = d_in[13];
  const void* mlpb0  = d_in[14];
  const void* mlpW1  = d_in[15];
  const void* mlpb1  = d_in[16];
  const void* mlpW2  = d_in[17];
  const void* mlpb2  = d_in[18];
  const void* mlpW3  = d_in[19];
  const void* mlpb3  = d_in[20];
  const void* predW0 = d_in[21];
  const void* predb0 = d_in[22];
  const void* predW1 = d_in[23];
  const void* predb1 = d_in[24];
  const void* outW   = d_in[25];
  const void* outb   = d_in[26];

  char* base = (char*)d_ws;
  size_t off = 0;
  auto alloc = [&](size_t bytes) -> char* {
    char* p = base + off;
    off = (off + bytes + 255) & ~(size_t)255;
    return p;
  };
  float* bufA     = (float*)alloc((size_t)NN * HID * 4);
  float* bufB     = (float*)alloc((size_t)NN * HID * 4);
  float* dinv_all = (float*)alloc((size_t)NL * NN * 4);
  int*   cnt      = (int*)alloc((size_t)NN * 4);
  int*   offs     = (int*)alloc((size_t)(NN + 1) * 4);
  int*   cursor   = (int*)alloc((size_t)NN * 4);
  int*   csr_src  = (int*)alloc((size_t)EE * 4);
  int*   csr_eid  = (int*)alloc((size_t)EE * 4);
  float* csr_val  = (float*)alloc((size_t)NL * EE * 4);
  unsigned short* Wt    = (unsigned short*)alloc((size_t)8 * HID * HID * 2);
  unsigned short* tailW = (unsigned short*)alloc((size_t)622592 * 2);
  unsigned short* edgeW = (unsigned short*)alloc((size_t)256 * 32 * 2);
  int*   flag     = (int*)alloc(256);
  float* molf32   = (float*)alloc((size_t)GG * 256 * 4);
  float* m0       = (float*)alloc((size_t)GG * MH * 4);
  float* m1       = (float*)alloc((size_t)GG * MH * 4);
  float* cat      = (float*)alloc((size_t)GG * PIN * 4);
  float* p0       = (float*)alloc((size_t)GG * PH * 4);
  float* p1       = (float*)alloc((size_t)GG * PH * 4);

  hipMemsetAsync(cnt, 0, (size_t)NN * 4, stream);
  hipMemsetAsync(cursor, 0, (size_t)NN * 4, stream);
  hipMemsetAsync(molf32, 0, (size_t)GG * 256 * 4, stream);

  // dtype probe first — everything downstream branches on it
  probe_kernel<<<1, 64, 0, stream>>>((const unsigned short*)x, flag);

  // weight prep
  prep_weights<<<512, 256, 0, stream>>>(lin_W, gW, Wt, flag);
  prep_tail<<<(622592 + 255) / 256, 256, 0, stream>>>(mlpW0, mlpW1, mlpW2, mlpW3,
                                                      predW0, predW1, tailW, flag);
  prep_edge_w<<<32, 256, 0, stream>>>(mW1, edgeW, flag);

  // x -> f32
  {
    int n4 = NN * HID / 4;
    cvt_any<<<(n4 + 255) / 256, 256, 0, stream>>>(x, bufA, n4, flag);
  }
  // CSR build
  count_kernel<<<(EE + 255) / 256, 256, 0, stream>>>(ei, cnt);
  scan_kernel<<<1, 256, 0, stream>>>(cnt, offs);
  fill_kernel<<<(EE + 255) / 256, 256, 0, stream>>>(ei, offs, cursor, csr_src, csr_eid);
  // edge gates (MFMA, CSR order), degrees, scaling
  edge_mlp_mfma<<<EE / 64, 256, 0, stream>>>(eattr, edgeW, mb1, mW2, mb2,
                                             csr_eid, csr_val, flag);
  deg_kernel<<<(NN + 255) / 256, 256, 0, stream>>>(offs, csr_val, dinv_all);
  csr_scale_kernel<<<(EE + 255) / 256, 256, 0, stream>>>(csr_src, dinv_all, csr_val);

  // GCN layers
  float* h = bufA;
  float* t = bufB;
  const int gemm_blocks = (NN + 63) / 64;  // 782
  for (int l = 0; l < NL; l++) {
    gemm_nodes_mfma<<<gemm_blocks, 256, 0, stream>>>(
        h, Wt + (size_t)l * HID * HID, nullptr, -1, t, 0, flag);
    aggregate_kernel<<<NN, 128, 0, stream>>>(t, offs, csr_src, csr_val + (size_t)l * EE,
                                             dinv_all + (size_t)l * NN, cbias,
                                             (long)l * HID, h, flag);
    gemm_nodes_mfma<<<gemm_blocks, 256, 0, stream>>>(
        h, Wt + (size_t)(4 + l) * HID * HID, gb, (long)l * HID, t, 1, flag);
    float* tmp = h; h = t; t = tmp;
  }

  // pooling -> cat[:, 0:128]
  pool_kernel<<<GG, 128, 0, stream>>>(h, batch, cat);

  // molecular MLP -> cat[:, 128:256]  (MFMA tail, K-padded weights)
  cvt_molf<<<(GG * 50 + 255) / 256, 256, 0, stream>>>(molf, molf32, flag);
  gemm_tail_mfma<<<dim3(4, 4), 256, 0, stream>>>(molf32, 256, tailW + 0,      256, mlpb0, m0, 256, 1, flag);
  gemm_tail_mfma<<<dim3(4, 4), 256, 0, stream>>>(m0,     256, tailW + 65536,  256, mlpb1, m1, 256, 1, flag);
  gemm_tail_mfma<<<dim3(4, 4), 256, 0, stream>>>(m1,     256, tailW + 131072, 256, mlpb2, m0, 256, 1, flag);
  gemm_tail_mfma<<<dim3(4, 2), 256, 0, stream>>>(m0,     256, tailW + 196608, 256, mlpb3, cat + MOUT, 256, 1, flag);

  // predictor
  gemm_tail_mfma<<<dim3(4, 8), 256, 0, stream>>>(cat, 256, tailW + 229376, 256, predb0, p0, 512, 1, flag);
  gemm_tail_mfma<<<dim3(4, 8), 256, 0, stream>>>(p0,  512, tailW + 360448, 512, predb1, p1, 512, 1, flag);
  final_kernel<<<GG, 64, 0, stream>>>(p1, outW, outb, d_out, flag);
}

// Round 7
// 803.931 us; speedup vs baseline: 6.6120x; 1.1005x over previous
//
#include <hip/hip_runtime.h>
#include <hip/hip_bf16.h>

// ---------------------------------------------------------------------------
// PDNConv GNN, MI355X round 7.
// Round-6 profile: the single-block strip scan was the #1 dispatch (87 us,
// occupancy 0.045% — three serial latency chains). Replaced with a 3-phase
// hierarchical scan (block-reduce -> scan block sums -> block prefix+offset),
// all coalesced, ~8 us total. Everything else unchanged from round 6.
// ---------------------------------------------------------------------------

#define NN 50000
#define EE 600000
#define GG 256
#define HID 128
#define EDIM 16
#define EHID 64
#define NL 4
#define MIN_F 200
#define MH 256
#define MOUT 128
#define PH 512
#define PIN 256
#define SCAN_B 196  // ceil(NN/256)

typedef __hip_bfloat16 bf16;
typedef __attribute__((ext_vector_type(8))) short bf16x8;
typedef __attribute__((ext_vector_type(4))) float f32x4;

__device__ __forceinline__ float bfl(unsigned u) { return __uint_as_float(u << 16); }
__device__ __forceinline__ float bfh(unsigned u) { return __uint_as_float(u & 0xffff0000u); }
__device__ __forceinline__ float b2f(bf16 x) { return __bfloat162float(x); }
__device__ __forceinline__ float ldf(const void* p, long i, bool bf) {
  return bf ? __bfloat162float(((const bf16*)p)[i]) : ((const float*)p)[i];
}
__device__ __forceinline__ unsigned short f2bf_bits(float v) {
  bf16 h = __float2bfloat16(v);
  return *reinterpret_cast<unsigned short*>(&h);
}

// ---------------- dtype probe ------------------------------------------------
__global__ void probe_kernel(const unsigned short* __restrict__ xs, int* flag) {
  if (threadIdx.x == 0 && blockIdx.x == 0) {
    int sane = 0;
    for (int i = 0; i < 128; i++) {
      unsigned e = (xs[i] >> 7) & 0xFF;
      if (e >= 96 && e <= 159) sane++;
    }
    *flag = (sane >= 112) ? 1 : 0;  // 1 = bf16 inputs
  }
}

// ---------------- input -> f32 conversion (4 elems/thread) ------------------
__global__ __launch_bounds__(256) void cvt_any(const void* __restrict__ in,
                                               float* __restrict__ outp, int n4,
                                               const int* __restrict__ flag) {
  bool bf = *flag != 0;
  int i = blockIdx.x * 256 + threadIdx.x;
  if (i >= n4) return;
  float4 v;
  if (bf) {
    uint2 u = reinterpret_cast<const uint2*>(in)[i];
    v.x = bfl(u.x); v.y = bfh(u.x); v.z = bfl(u.y); v.w = bfh(u.y);
  } else {
    v = reinterpret_cast<const float4*>(in)[i];
  }
  reinterpret_cast<float4*>(outp)[i] = v;
}

// ---------------- mol_features [G,200] -> padded f32 [G,256] ----------------
__global__ __launch_bounds__(256) void cvt_molf(const void* __restrict__ in,
                                                float* __restrict__ outp,
                                                const int* __restrict__ flag) {
  bool bf = *flag != 0;
  int i = blockIdx.x * 256 + threadIdx.x;  // GG*50
  if (i >= GG * 50) return;
  int row = i / 50, c4 = (i % 50) * 4;
  float4 v;
  if (bf) {
    const unsigned short* p = (const unsigned short*)in + (size_t)row * MIN_F + c4;
    uint2 u = *reinterpret_cast<const uint2*>(p);
    v.x = bfl(u.x); v.y = bfh(u.x); v.z = bfl(u.y); v.w = bfh(u.y);
  } else {
    v = *reinterpret_cast<const float4*>((const float*)in + (size_t)row * MIN_F + c4);
  }
  *reinterpret_cast<float4*>(&outp[(size_t)row * 256 + c4]) = v;
}

// ---------------- weight prep: node GEMM weights -> bf16 Wt[n][k] -----------
__global__ __launch_bounds__(256) void prep_weights(const void* __restrict__ lin_W,
                                                    const void* __restrict__ gW,
                                                    unsigned short* __restrict__ Wt,
                                                    const int* __restrict__ flag) {
  bool bf = *flag != 0;
  int idx = blockIdx.x * 256 + threadIdx.x;  // 0 .. 8*16384-1
  if (idx >= 8 * 16384) return;
  int mat = idx >> 14;
  int rem = idx & 16383;
  int n = rem >> 7, k = rem & 127;
  const void* src = (mat < 4) ? lin_W : gW;
  long srcIdx = (long)(mat & 3) * 16384 + (long)k * 128 + n;
  Wt[idx] = f2bf_bits(ldf(src, srcIdx, bf));
}

// ---------------- weight prep: edge MLP W1 -> bf16 W1t[256 cols][32 K] ------
__global__ __launch_bounds__(256) void prep_edge_w(const void* __restrict__ mW1,
                                                   unsigned short* __restrict__ W1t,
                                                   const int* __restrict__ flag) {
  bool bf = *flag != 0;
  int idx = blockIdx.x * 256 + threadIdx.x;  // 256*32
  if (idx >= 256 * 32) return;
  int col = idx >> 5, k = idx & 31;
  float v = 0.f;
  if (k < EDIM) v = ldf(mW1, (long)(col >> 6) * (EDIM * EHID) + (long)k * EHID + (col & 63), bf);
  W1t[idx] = f2bf_bits(v);
}

// ---------------- weight prep: tail (MLP+predictor) -> bf16 [N][Kp], K-pad --
__global__ __launch_bounds__(256) void prep_tail(
    const void* __restrict__ mlpW0, const void* __restrict__ mlpW1,
    const void* __restrict__ mlpW2, const void* __restrict__ mlpW3,
    const void* __restrict__ predW0, const void* __restrict__ predW1,
    unsigned short* __restrict__ T, const int* __restrict__ flag) {
  bool bf = *flag != 0;
  int idx = blockIdx.x * 256 + threadIdx.x;
  const void* src; int N, Kp, Ksrc, off;
  if      (idx < 65536)  { src = mlpW0;  N = 256; Kp = 256; Ksrc = 200; off = 0; }
  else if (idx < 131072) { src = mlpW1;  N = 256; Kp = 256; Ksrc = 256; off = 65536; }
  else if (idx < 196608) { src = mlpW2;  N = 256; Kp = 256; Ksrc = 256; off = 131072; }
  else if (idx < 229376) { src = mlpW3;  N = 128; Kp = 256; Ksrc = 256; off = 196608; }
  else if (idx < 360448) { src = predW0; N = 512; Kp = 256; Ksrc = 256; off = 229376; }
  else if (idx < 622592) { src = predW1; N = 512; Kp = 512; Ksrc = 512; off = 360448; }
  else return;
  int rem = idx - off;
  int n = rem / Kp, k = rem % Kp;
  float v = (k < Ksrc) ? ldf(src, (long)k * N + n, bf) : 0.f;
  T[idx] = f2bf_bits(v);
}

// ---------------- CSR build: histogram / 3-phase scan / fill ----------------
__global__ __launch_bounds__(256) void count_kernel(const int* __restrict__ ei,
                                                    int* __restrict__ cnt) {
  int e = blockIdx.x * 256 + threadIdx.x;
  if (e >= EE) return;
  int c = ei[EE + e];
  c = min(max(c, 0), NN - 1);
  atomicAdd(&cnt[c], 1);
}

__global__ __launch_bounds__(256) void scan_phase1(const int* __restrict__ cnt,
                                                   int* __restrict__ bsum) {
  __shared__ int red[256];
  int tid = threadIdx.x;
  int i = blockIdx.x * 256 + tid;
  red[tid] = (i < NN) ? cnt[i] : 0;
  __syncthreads();
  for (int off = 128; off > 0; off >>= 1) {
    if (tid < off) red[tid] += red[tid + off];
    __syncthreads();
  }
  if (tid == 0) bsum[blockIdx.x] = red[0];
}

__global__ __launch_bounds__(256) void scan_phase2(int* __restrict__ bsum,
                                                   int* __restrict__ offs) {
  __shared__ int buf[256];
  int tid = threadIdx.x;
  int v = (tid < SCAN_B) ? bsum[tid] : 0;
  buf[tid] = v;
  __syncthreads();
  for (int off = 1; off < 256; off <<= 1) {
    int t = (tid >= off) ? buf[tid - off] : 0;
    __syncthreads();
    buf[tid] += t;
    __syncthreads();
  }
  if (tid < SCAN_B) bsum[tid] = buf[tid] - v;  // exclusive block offsets
  if (tid == 255) offs[NN] = buf[255];
}

__global__ __launch_bounds__(256) void scan_phase3(const int* __restrict__ cnt,
                                                   const int* __restrict__ bsum,
                                                   int* __restrict__ offs) {
  __shared__ int buf[256];
  int tid = threadIdx.x;
  int i = blockIdx.x * 256 + tid;
  int v = (i < NN) ? cnt[i] : 0;
  buf[tid] = v;
  __syncthreads();
  for (int off = 1; off < 256; off <<= 1) {
    int t = (tid >= off) ? buf[tid - off] : 0;
    __syncthreads();
    buf[tid] += t;
    __syncthreads();
  }
  if (i < NN) offs[i] = bsum[blockIdx.x] + buf[tid] - v;
}

__global__ __launch_bounds__(256) void fill_kernel(const int* __restrict__ ei,
                                                   const int* __restrict__ offs,
                                                   int* __restrict__ cursor,
                                                   int* __restrict__ csr_src,
                                                   int* __restrict__ csr_eid) {
  int e = blockIdx.x * 256 + threadIdx.x;
  if (e >= EE) return;
  int c = ei[EE + e];
  c = min(max(c, 0), NN - 1);
  int pos = offs[c] + atomicAdd(&cursor[c], 1);
  pos = min(max(pos, 0), EE - 1);
  csr_src[pos] = ei[e];
  csr_eid[pos] = e;
}

// ---------------- edge-gate MLP via MFMA (all 4 layers, CSR order) ----------
__global__ __launch_bounds__(256) void edge_mlp_mfma(
    const void* __restrict__ eattr, const unsigned short* __restrict__ W1t,
    const void* __restrict__ mb1, const void* __restrict__ mW2,
    const void* __restrict__ mb2, const int* __restrict__ csr_eid,
    float* __restrict__ csr_val, const int* __restrict__ flag) {
  bool bf = *flag != 0;
  __shared__ alignas(16) unsigned short sW[256 * 40];
  __shared__ alignas(16) unsigned short sA[64 * 40];
  __shared__ float sb1f[256];
  __shared__ float sw2f[256];
  __shared__ float sb2f[NL];
  int tid = threadIdx.x;
  int rbase = blockIdx.x * 64;

#pragma unroll
  for (int p = 0; p < 4; p++) {
    int idx8 = p * 256 + tid;
    int n = idx8 >> 2, kc = (idx8 & 3) * 8;
    uint4 v = reinterpret_cast<const uint4*>(W1t)[idx8];
    *reinterpret_cast<uint4*>(&sW[n * 40 + kc]) = v;
  }
  sb1f[tid] = ldf(mb1, tid, bf);
  sw2f[tid] = ldf(mW2, tid, bf);
  if (tid < NL) sb2f[tid] = ldf(mb2, tid, bf);

  {
    int e = tid >> 2, q = tid & 3;
    ushort4 z; z.x = 0; z.y = 0; z.z = 0; z.w = 0;
    *reinterpret_cast<ushort4*>(&sA[e * 40 + 16 + q * 4]) = z;
  }
  if (bf) {
    if (tid < 128) {
      int e = tid >> 1, half = tid & 1;
      long eid = csr_eid[rbase + e];
      uint4 v = reinterpret_cast<const uint4*>((const bf16*)eattr + eid * EDIM)[half];
      *reinterpret_cast<uint4*>(&sA[e * 40 + half * 8]) = v;
    }
  } else {
    int e = tid >> 2, q = tid & 3;
    long eid = csr_eid[rbase + e];
    float4 v = reinterpret_cast<const float4*>((const float*)eattr + eid * EDIM)[q];
    ushort4 b;
    b.x = f2bf_bits(v.x); b.y = f2bf_bits(v.y);
    b.z = f2bf_bits(v.z); b.w = f2bf_bits(v.w);
    *reinterpret_cast<ushort4*>(&sA[e * 40 + q * 4]) = b;
  }
  __syncthreads();

  int wave = tid >> 6, lane = tid & 63;
  int l15 = lane & 15, quad = lane >> 4;
  int mstrip = wave * 16;

  bf16x8 a = *reinterpret_cast<const bf16x8*>(&sA[(mstrip + l15) * 40 + quad * 8]);
  f32x4 acc[16];
#pragma unroll
  for (int t = 0; t < 16; t++) {
    bf16x8 b = *reinterpret_cast<const bf16x8*>(&sW[(t * 16 + l15) * 40 + quad * 8]);
    acc[t] = __builtin_amdgcn_mfma_f32_16x16x32_bf16(a, b, (f32x4){0.f, 0.f, 0.f, 0.f},
                                                     0, 0, 0);
  }

  float s[NL][4];
#pragma unroll
  for (int l = 0; l < NL; l++) {
#pragma unroll
    for (int r = 0; r < 4; r++) s[l][r] = 0.f;
#pragma unroll
    for (int tt = 0; tt < 4; tt++) {
      int t = l * 4 + tt;
      int col = t * 16 + l15;
      float b1v = sb1f[col], w2v = sw2f[col];
#pragma unroll
      for (int r = 0; r < 4; r++)
        s[l][r] += fmaxf(acc[t][r] + b1v, 0.f) * w2v;
    }
  }
#pragma unroll
  for (int m = 1; m <= 8; m <<= 1) {
#pragma unroll
    for (int l = 0; l < NL; l++)
#pragma unroll
      for (int r = 0; r < 4; r++) s[l][r] += __shfl_xor(s[l][r], m);
  }
  if (l15 < NL) {
    int l = l15;
    float b2v = sb2f[l];
#pragma unroll
    for (int r = 0; r < 4; r++) {
      int e = rbase + mstrip + quad * 4 + r;
      csr_val[(size_t)l * EE + e] = 1.f / (1.f + __expf(-(s[l][r] + b2v)));
    }
  }
}

// ---------------- degree / dinv per layer -----------------------------------
__global__ __launch_bounds__(256) void deg_kernel(const int* __restrict__ offs,
                                                  const float* __restrict__ csr_val,
                                                  float* __restrict__ dinv_all) {
  int n = blockIdx.x * 256 + threadIdx.x;
  if (n >= NN) return;
  int s = offs[n], e = offs[n + 1];
  float d0 = 1.f, d1 = 1.f, d2 = 1.f, d3 = 1.f;  // self-loop weight 1.0
  for (int k = s; k < e; k++) {
    d0 += csr_val[k];
    d1 += csr_val[EE + k];
    d2 += csr_val[2 * (size_t)EE + k];
    d3 += csr_val[3 * (size_t)EE + k];
  }
  dinv_all[n] = rsqrtf(d0);
  dinv_all[NN + n] = rsqrtf(d1);
  dinv_all[2 * NN + n] = rsqrtf(d2);
  dinv_all[3 * NN + n] = rsqrtf(d3);
}

// csr_val[l][k] *= dinv_l[src_k]
__global__ __launch_bounds__(256) void csr_scale_kernel(const int* __restrict__ csr_src,
                                                        const float* __restrict__ dinv_all,
                                                        float* __restrict__ csr_val) {
  int k = blockIdx.x * 256 + threadIdx.x;
  if (k >= EE) return;
  int s = csr_src[k];
  s = min(max(s, 0), NN - 1);
#pragma unroll
  for (int l = 0; l < NL; l++)
    csr_val[(size_t)l * EE + k] *= dinv_all[(size_t)l * NN + s];
}

// ---------------- node GEMM via MFMA ----------------------------------------
__global__ __launch_bounds__(256) void gemm_nodes_mfma(
    const float* __restrict__ A, const unsigned short* __restrict__ Wt,
    const void* __restrict__ bias, long boff, float* __restrict__ outp,
    int relu, const int* __restrict__ flag) {
  __shared__ alignas(16) unsigned short sA[64 * 136];
  __shared__ alignas(16) unsigned short sW[128 * 136];
  int tid = threadIdx.x;
  int rbase = blockIdx.x * 64;

#pragma unroll
  for (int p = 0; p < 8; p++) {
    int idx8 = p * 256 + tid;
    int n = idx8 >> 4, kc = idx8 & 15;
    uint4 v = reinterpret_cast<const uint4*>(Wt)[idx8];
    *reinterpret_cast<uint4*>(&sW[n * 136 + kc * 8]) = v;
  }
#pragma unroll
  for (int p = 0; p < 8; p++) {
    int idx = p * 1024 + tid * 4;
    int m = idx >> 7, k = idx & 127;
    int row = rbase + m;
    float4 v = make_float4(0.f, 0.f, 0.f, 0.f);
    if (row < NN) v = *reinterpret_cast<const float4*>(&A[(size_t)row * HID + k]);
    ushort4 b;
    b.x = f2bf_bits(v.x); b.y = f2bf_bits(v.y);
    b.z = f2bf_bits(v.z); b.w = f2bf_bits(v.w);
    *reinterpret_cast<ushort4*>(&sA[m * 136 + k]) = b;
  }
  __syncthreads();

  int wave = tid >> 6, lane = tid & 63;
  int l15 = lane & 15, quad = lane >> 4;
  int mstrip = wave * 16;

  f32x4 acc[8];
#pragma unroll
  for (int t = 0; t < 8; t++) acc[t] = (f32x4){0.f, 0.f, 0.f, 0.f};

#pragma unroll
  for (int ks = 0; ks < 4; ks++) {
    int k0 = ks * 32 + quad * 8;
    bf16x8 a = *reinterpret_cast<const bf16x8*>(&sA[(mstrip + l15) * 136 + k0]);
#pragma unroll
    for (int t = 0; t < 8; t++) {
      bf16x8 b = *reinterpret_cast<const bf16x8*>(&sW[(t * 16 + l15) * 136 + k0]);
      acc[t] = __builtin_amdgcn_mfma_f32_16x16x32_bf16(a, b, acc[t], 0, 0, 0);
    }
  }

  bool bf = *flag != 0;
#pragma unroll
  for (int t = 0; t < 8; t++) {
    int n = t * 16 + l15;
    float bv = (boff >= 0) ? ldf(bias, boff + n, bf) : 0.f;
#pragma unroll
    for (int r = 0; r < 4; r++) {
      int row = rbase + mstrip + quad * 4 + r;
      if (row < NN) {
        float o = acc[t][r] + bv;
        if (relu) o = fmaxf(o, 0.f);
        outp[(size_t)row * HID + n] = o;
      }
    }
  }
}

// ---------------- tail GEMM via MFMA ----------------------------------------
__global__ __launch_bounds__(256) void gemm_tail_mfma(
    const float* __restrict__ A, int lda, const unsigned short* __restrict__ Wt,
    int Kp, const void* __restrict__ bias, float* __restrict__ outp, int ldo,
    int relu, const int* __restrict__ flag) {
  __shared__ alignas(16) unsigned short sA[64 * 264];
  __shared__ alignas(16) unsigned short sW[64 * 264];
  int tid = threadIdx.x;
  int rbase = blockIdx.x * 64;
  int nbase = blockIdx.y * 64;
  int wave = tid >> 6, lane = tid & 63;
  int l15 = lane & 15, quad = lane >> 4;
  int mstrip = wave * 16;

  f32x4 acc[4];
#pragma unroll
  for (int t = 0; t < 4; t++) acc[t] = (f32x4){0.f, 0.f, 0.f, 0.f};

  for (int kc = 0; kc < Kp; kc += 256) {
#pragma unroll 4
    for (int p = 0; p < 16; p++) {
      int idx = p * 1024 + tid * 4;
      int m = idx >> 8, k = idx & 255;
      float4 v = *reinterpret_cast<const float4*>(&A[(size_t)(rbase + m) * lda + kc + k]);
      ushort4 b;
      b.x = f2bf_bits(v.x); b.y = f2bf_bits(v.y);
      b.z = f2bf_bits(v.z); b.w = f2bf_bits(v.w);
      *reinterpret_cast<ushort4*>(&sA[m * 264 + k]) = b;
    }
#pragma unroll 4
    for (int p = 0; p < 8; p++) {
      int idx8 = p * 256 + tid;
      int n = idx8 >> 5, kk = (idx8 & 31) * 8;
      uint4 v = *reinterpret_cast<const uint4*>(&Wt[(size_t)(nbase + n) * Kp + kc + kk]);
      *reinterpret_cast<uint4*>(&sW[n * 264 + kk]) = v;
    }
    __syncthreads();
#pragma unroll
    for (int ks = 0; ks < 8; ks++) {
      int k0 = ks * 32 + quad * 8;
      bf16x8 a = *reinterpret_cast<const bf16x8*>(&sA[(mstrip + l15) * 264 + k0]);
#pragma unroll
      for (int nt = 0; nt < 4; nt++) {
        bf16x8 b = *reinterpret_cast<const bf16x8*>(&sW[(nt * 16 + l15) * 264 + k0]);
        acc[nt] = __builtin_amdgcn_mfma_f32_16x16x32_bf16(a, b, acc[nt], 0, 0, 0);
      }
    }
    __syncthreads();
  }

  bool bf = *flag != 0;
#pragma unroll
  for (int nt = 0; nt < 4; nt++) {
    int col = nbase + nt * 16 + l15;
    float bv = ldf(bias, col, bf);
#pragma unroll
    for (int r = 0; r < 4; r++) {
      int row = rbase + mstrip + quad * 4 + r;
      float o = acc[nt][r] + bv;
      if (relu) o = fmaxf(o, 0.f);
      outp[(size_t)row * ldo + col] = o;
    }
  }
}

// ---------------- aggregation ------------------------------------------------
__global__ __launch_bounds__(128) void aggregate_kernel(const float* __restrict__ hl,
                                                        const int* __restrict__ offs,
                                                        const int* __restrict__ csr_src,
                                                        const float* __restrict__ csr_val,
                                                        const float* __restrict__ dinv,
                                                        const void* __restrict__ bias, long boff,
                                                        float* __restrict__ outp,
                                                        const int* __restrict__ flag) {
  bool bf = *flag != 0;
  int n = blockIdx.x;
  int c = threadIdx.x;
  __shared__ int s_src[128];
  __shared__ float s_val[128];
  int start = offs[n], end = offs[n + 1];
  float acc = 0.f;
  for (int base = start; base < end; base += 128) {
    int k = base + c;
    if (k < end) {
      int sr = csr_src[k];
      s_src[c] = min(max(sr, 0), NN - 1);
      s_val[c] = csr_val[k];
    }
    __syncthreads();
    int m = min(128, end - base);
    for (int j = 0; j < m; j++)
      acc = fmaf(s_val[j], hl[(size_t)s_src[j] * HID + c], acc);
    __syncthreads();
  }
  float dn = dinv[n];
  outp[(size_t)n * HID + c] =
      dn * acc + dn * dn * hl[(size_t)n * HID + c] + ldf(bias, boff + c, bf);
}

// ---------------- mean pool per graph (sorted batch_index) ------------------
__global__ __launch_bounds__(128) void pool_kernel(const float* __restrict__ h,
                                                   const int* __restrict__ batch,
                                                   float* __restrict__ cat) {
  int g = blockIdx.x, c = threadIdx.x;
  int lo = 0, hi = NN;
  while (lo < hi) { int mid = (lo + hi) >> 1; if (batch[mid] < g) lo = mid + 1; else hi = mid; }
  int start = lo;
  hi = NN;
  while (lo < hi) { int mid = (lo + hi) >> 1; if (batch[mid] < g + 1) lo = mid + 1; else hi = mid; }
  int end = lo;
  float s = 0.f;
  for (int n = start; n < end; n++) s += h[(size_t)n * HID + c];
  float cntf = (float)(end - start);
  cat[(size_t)g * PIN + c] = s / fmaxf(cntf, 1.f);
}

// ---------------- final [G,512] @ [512,1] + b -> out ------------------------
__global__ __launch_bounds__(64) void final_kernel(const float* __restrict__ A,
                                                   const void* __restrict__ W,
                                                   const void* __restrict__ b,
                                                   void* __restrict__ outp,
                                                   const int* __restrict__ flag) {
  bool bf = *flag != 0;
  int g = blockIdx.x, lane = threadIdx.x;
  float s = 0.f;
  for (int k = lane; k < PH; k += 64) s = fmaf(A[(size_t)g * PH + k], ldf(W, k, bf), s);
#pragma unroll
  for (int off = 32; off > 0; off >>= 1) s += __shfl_down(s, off);
  if (lane == 0) {
    float r = s + ldf(b, 0, bf);
    if (bf) ((bf16*)outp)[g] = __float2bfloat16(r);
    else    ((float*)outp)[g] = r;
  }
}

// ---------------------------------------------------------------------------
extern "C" void kernel_launch(void* const* d_in, const int* in_sizes, int n_in,
                              void* d_out, int out_size, void* d_ws, size_t ws_size,
                              hipStream_t stream) {
  const void* x      = d_in[0];
  const int*  ei     = (const int*)d_in[1];
  const void* eattr  = d_in[2];
  const int*  batch  = (const int*)d_in[3];
  const void* molf   = d_in[4];
  const void* lin_W  = d_in[5];
  const void* mW1    = d_in[6];
  const void* mb1    = d_in[7];
  const void* mW2    = d_in[8];
  const void* mb2    = d_in[9];
  const void* cbias  = d_in[10];
  const void* gW     = d_in[11];
  const void* gb     = d_in[12];
  const void* mlpW0  = d_in[13];
  const void* mlpb0  = d_in[14];
  const void* mlpW1  = d_in[15];
  const void* mlpb1  = d_in[16];
  const void* mlpW2  = d_in[17];
  const void* mlpb2  = d_in[18];
  const void* mlpW3  = d_in[19];
  const void* mlpb3  = d_in[20];
  const void* predW0 = d_in[21];
  const void* predb0 = d_in[22];
  const void* predW1 = d_in[23];
  const void* predb1 = d_in[24];
  const void* outW   = d_in[25];
  const void* outb   = d_in[26];

  char* base = (char*)d_ws;
  size_t off = 0;
  auto alloc = [&](size_t bytes) -> char* {
    char* p = base + off;
    off = (off + bytes + 255) & ~(size_t)255;
    return p;
  };
  float* bufA     = (float*)alloc((size_t)NN * HID * 4);
  float* bufB     = (float*)alloc((size_t)NN * HID * 4);
  float* dinv_all = (float*)alloc((size_t)NL * NN * 4);
  int*   cnt      = (int*)alloc((size_t)NN * 4);
  int*   offs     = (int*)alloc((size_t)(NN + 1) * 4);
  int*   cursor   = (int*)alloc((size_t)NN * 4);
  int*   bsum     = (int*)alloc((size_t)256 * 4);
  int*   csr_src  = (int*)alloc((size_t)EE * 4);
  int*   csr_eid  = (int*)alloc((size_t)EE * 4);
  float* csr_val  = (float*)alloc((size_t)NL * EE * 4);
  unsigned short* Wt    = (unsigned short*)alloc((size_t)8 * HID * HID * 2);
  unsigned short* tailW = (unsigned short*)alloc((size_t)622592 * 2);
  unsigned short* edgeW = (unsigned short*)alloc((size_t)256 * 32 * 2);
  int*   flag     = (int*)alloc(256);
  float* molf32   = (float*)alloc((size_t)GG * 256 * 4);
  float* m0       = (float*)alloc((size_t)GG * MH * 4);
  float* m1       = (float*)alloc((size_t)GG * MH * 4);
  float* cat      = (float*)alloc((size_t)GG * PIN * 4);
  float* p0       = (float*)alloc((size_t)GG * PH * 4);
  float* p1       = (float*)alloc((size_t)GG * PH * 4);

  hipMemsetAsync(cnt, 0, (size_t)NN * 4, stream);
  hipMemsetAsync(cursor, 0, (size_t)NN * 4, stream);
  hipMemsetAsync(molf32, 0, (size_t)GG * 256 * 4, stream);

  // dtype probe first — everything downstream branches on it
  probe_kernel<<<1, 64, 0, stream>>>((const unsigned short*)x, flag);

  // weight prep
  prep_weights<<<512, 256, 0, stream>>>(lin_W, gW, Wt, flag);
  prep_tail<<<(622592 + 255) / 256, 256, 0, stream>>>(mlpW0, mlpW1, mlpW2, mlpW3,
                                                      predW0, predW1, tailW, flag);
  prep_edge_w<<<32, 256, 0, stream>>>(mW1, edgeW, flag);

  // x -> f32
  {
    int n4 = NN * HID / 4;
    cvt_any<<<(n4 + 255) / 256, 256, 0, stream>>>(x, bufA, n4, flag);
  }
  // CSR build (3-phase parallel scan)
  count_kernel<<<(EE + 255) / 256, 256, 0, stream>>>(ei, cnt);
  scan_phase1<<<SCAN_B, 256, 0, stream>>>(cnt, bsum);
  scan_phase2<<<1, 256, 0, stream>>>(bsum, offs);
  scan_phase3<<<SCAN_B, 256, 0, stream>>>(cnt, bsum, offs);
  fill_kernel<<<(EE + 255) / 256, 256, 0, stream>>>(ei, offs, cursor, csr_src, csr_eid);
  // edge gates (MFMA, CSR order), degrees, scaling
  edge_mlp_mfma<<<EE / 64, 256, 0, stream>>>(eattr, edgeW, mb1, mW2, mb2,
                                             csr_eid, csr_val, flag);
  deg_kernel<<<(NN + 255) / 256, 256, 0, stream>>>(offs, csr_val, dinv_all);
  csr_scale_kernel<<<(EE + 255) / 256, 256, 0, stream>>>(csr_src, dinv_all, csr_val);

  // GCN layers
  float* h = bufA;
  float* t = bufB;
  const int gemm_blocks = (NN + 63) / 64;  // 782
  for (int l = 0; l < NL; l++) {
    gemm_nodes_mfma<<<gemm_blocks, 256, 0, stream>>>(
        h, Wt + (size_t)l * HID * HID, nullptr, -1, t, 0, flag);
    aggregate_kernel<<<NN, 128, 0, stream>>>(t, offs, csr_src, csr_val + (size_t)l * EE,
                                             dinv_all + (size_t)l * NN, cbias,
                                             (long)l * HID, h, flag);
    gemm_nodes_mfma<<<gemm_blocks, 256, 0, stream>>>(
        h, Wt + (size_t)(4 + l) * HID * HID, gb, (long)l * HID, t, 1, flag);
    float* tmp = h; h = t; t = tmp;
  }

  // pooling -> cat[:, 0:128]
  pool_kernel<<<GG, 128, 0, stream>>>(h, batch, cat);

  // molecular MLP -> cat[:, 128:256]  (MFMA tail, K-padded weights)
  cvt_molf<<<(GG * 50 + 255) / 256, 256, 0, stream>>>(molf, molf32, flag);
  gemm_tail_mfma<<<dim3(4, 4), 256, 0, stream>>>(molf32, 256, tailW + 0,      256, mlpb0, m0, 256, 1, flag);
  gemm_tail_mfma<<<dim3(4, 4), 256, 0, stream>>>(m0,     256, tailW + 65536,  256, mlpb1, m1, 256, 1, flag);
  gemm_tail_mfma<<<dim3(4, 4), 256, 0, stream>>>(m1,     256, tailW + 131072, 256, mlpb2, m0, 256, 1, flag);
  gemm_tail_mfma<<<dim3(4, 2), 256, 0, stream>>>(m0,     256, tailW + 196608, 256, mlpb3, cat + MOUT, 256, 1, flag);

  // predictor
  gemm_tail_mfma<<<dim3(4, 8), 256, 0, stream>>>(cat, 256, tailW + 229376, 256, predb0, p0, 512, 1, flag);
  gemm_tail_mfma<<<dim3(4, 8), 256, 0, stream>>>(p0,  512, tailW + 360448, 512, predb1, p1, 512, 1, flag);
  final_kernel<<<GG, 64, 0, stream>>>(p1, outW, outb, d_out, flag);
}